// Round 10
// baseline (248.770 us; speedup 1.0000x reference)
//
#include <hip/hip_runtime.h>

typedef _Float16 half8 __attribute__((ext_vector_type(8)));
typedef __fp16 fp16x2 __attribute__((ext_vector_type(2)));
typedef float floatx4 __attribute__((ext_vector_type(4)));
typedef unsigned int uint;
typedef uint uint4t __attribute__((ext_vector_type(4)));

namespace {
constexpr int TT = 48, HID = 64, MH = 32, MS = 20;
constexpr int NWAVES = 4;         // waves per block (independent bn)
// d_ws offsets in half elements (total 32768 halves = 64 KiB)
constexpr int WS_WV   = 0;        // value_w B-frags: [e][kk][nb] * 512
constexpr int WS_MEMA = 6144;     // mem A-frags (rows s, zero s>=20): 1024
constexpr int WS_MEMB = 7168;     // mem B-frags (k=s, col m, zero s>=20): 1024
constexpr int WS_M    = 8192;     // M^T A-frags: [e][hl][tbG][ak] * 512 (hl=1 unused)
}

static __device__ inline uint pk2(float a, float b) {
    fp16x2 h = __builtin_amdgcn_cvt_pkrtz(a, b);
    return __builtin_bit_cast(uint, h);
}
static __device__ inline half8 mk8(uint a, uint b, uint c, uint d) {
    uint4t u = {a, b, c, d};
    return __builtin_bit_cast(half8, u);
}
static __device__ inline uint pkadd(uint a, uint b) {
    fp16x2 x = __builtin_bit_cast(fp16x2, a);
    fp16x2 y = __builtin_bit_cast(fp16x2, b);
    fp16x2 z = x + y;                      // v_pk_add_f16
    return __builtin_bit_cast(uint, z);
}
static __device__ inline float f16lo(uint u) {
    fp16x2 f = __builtin_bit_cast(fp16x2, u); return (float)f[0];
}
static __device__ inline float f16hi(uint u) {
    fp16x2 f = __builtin_bit_cast(fp16x2, u); return (float)f[1];
}
// C-layout -> fragment regroup (verified rounds 6-9)
static __device__ inline half8 regroup2(const uint p0[2], const uint p1[2],
                                        int laneA, bool hiT) {
    uint w[4];
    #pragma unroll
    for (int d = 0; d < 2; ++d) {
        int a0 = __shfl((int)p0[d], laneA);
        int a1 = __shfl((int)p1[d], laneA);
        int b0 = __shfl((int)p0[d], laneA + 16);
        int b1 = __shfl((int)p1[d], laneA + 16);
        w[d]     = hiT ? (uint)a1 : (uint)a0;
        w[2 + d] = hiT ? (uint)b1 : (uint)b0;
    }
    return mk8(w[0], w[1], w[2], w[3]);
}
static __device__ inline half8 regroup1pad(const uint p2[2], int laneA, bool hiT) {
    uint w[4];
    #pragma unroll
    for (int d = 0; d < 2; ++d) {
        int a2 = __shfl((int)p2[d], laneA);
        int b2 = __shfl((int)p2[d], laneA + 16);
        w[d]     = hiT ? 0u : (uint)a2;
        w[2 + d] = hiT ? 0u : (uint)b2;
    }
    return mk8(w[0], w[1], w[2], w[3]);
}

// Prep: per-expert M = Wq*Wk^T (fp32) -> M^T A-frags; value_w B-frags; mem frags.
__global__ __launch_bounds__(256)
void prep_frags(const float* __restrict__ hid_query,
                const float* __restrict__ key_w,
                const float* __restrict__ value_w,
                const float* __restrict__ memory,
                _Float16* __restrict__ ws)
{
    const int e = blockIdx.x, tid = threadIdx.x;
    __shared__ float sWq[HID * MH], sWk[HID * MH], sM[HID * HID];
    for (int i = tid; i < HID * MH; i += 256) {
        sWq[i] = hid_query[e * HID * MH + i];
        sWk[i] = key_w[e * HID * MH + i];
    }
    __syncthreads();
    for (int i = tid; i < HID * HID; i += 256) {
        int a = i >> 6, b = i & 63;
        float acc = 0.f;
        #pragma unroll
        for (int m = 0; m < MH; ++m) acc = fmaf(sWq[a * MH + m], sWk[b * MH + m], acc);
        sM[i] = acc;
    }
    __syncthreads();
    for (int i = tid; i < 16 * 512; i += 256) {
        int j = i & 7, lane = (i >> 3) & 63, ak = (i >> 9) & 1, tbG = (i >> 10) & 3, hl = (i >> 12) & 1;
        float v = sM[(32 * ak + 8 * (lane >> 4) + j) * 64 + 16 * tbG + (lane & 15)];
        _Float16 hi = (_Float16)v;
        ws[WS_M + (size_t)((((e * 2 + hl) * 4 + tbG) * 2 + ak) << 9) + (i & 511)] =
            hl ? (_Float16)(v - (float)hi) : hi;
    }
    for (int i = tid; i < 2048; i += 256) {
        int j = i & 7, lane = (i >> 3) & 63, nb = (i >> 9) & 1, kk = (i >> 10) & 1;
        int h = kk * 32 + (lane >> 4) * 8 + j;
        int m = nb * 16 + (lane & 15);
        ws[WS_WV + e * 2048 + (i & 2047)] = (_Float16)value_w[((size_t)e * HID + h) * MH + m];
    }
    if (e == 0) {
        for (int i = tid; i < 1024; i += 256) {
            int j = i & 7, lane = (i >> 3) & 63, sb = i >> 9;
            int s = 16 * sb + (lane & 15);
            int m = (lane >> 4) * 8 + j;
            ws[WS_MEMA + i] = (s < MS) ? (_Float16)memory[s * MH + m] : (_Float16)0.f;
        }
        for (int i = tid; i < 1024; i += 256) {
            int j = i & 7, lane = (i >> 3) & 63, nb = i >> 9;
            int s = (lane >> 4) * 8 + j;
            int m = 16 * nb + (lane & 15);
            ws[WS_MEMB + i] = (s < MS) ? (_Float16)memory[s * MH + m] : (_Float16)0.f;
        }
    }
}

// One wave per bn, e-loop inside (phase A computed ONCE per bn). No LDS.
__global__ __launch_bounds__(256, 4)
void testam_wave(const float* __restrict__ input,
                 const float* __restrict__ h0,
                 const float* __restrict__ h1,
                 const float* __restrict__ h2,
                 const float* __restrict__ input_query,
                 const _Float16* __restrict__ ws,
                 float* __restrict__ out)
{
    const int tid  = threadIdx.x;
    const int wid  = tid >> 6;
    const int lane = tid & 63;
    const int r = lane & 15, g = lane >> 4;
    const size_t bn = (size_t)blockIdx.x * NWAVES + wid;

    const int laneA = (g & 1) * 32 + r;
    const bool hiT = (g >= 2);

    // ================= phase A (once per bn): memories + norms ==============
    uint  mems_pk[3][2][2];   // memories, f16-packed, C-layout pairs
    float nm_[3][4];          // |memories|^2 per t, reduced, valid in ALL lanes
    {
        half8 memA0 = *(const half8*)(ws + WS_MEMA + (size_t)lane * 8);
        half8 memA1 = *(const half8*)(ws + WS_MEMA + (size_t)(64 + lane) * 8);
        half8 memB0 = *(const half8*)(ws + WS_MEMB + (size_t)lane * 8);
        half8 memB1 = *(const half8*)(ws + WS_MEMB + (size_t)(64 + lane) * 8);

        float4 iqa = *(const float4*)(input_query + g * 8);
        float4 iqb = *(const float4*)(input_query + g * 8 + 4);
        float4 iqc = *(const float4*)(input_query + 32 + g * 8);
        float4 iqd = *(const float4*)(input_query + 32 + g * 8 + 4);
        float iq0[8] = {iqa.x, iqa.y, iqa.z, iqa.w, iqb.x, iqb.y, iqb.z, iqb.w};
        float iq1[8] = {iqc.x, iqc.y, iqc.z, iqc.w, iqd.x, iqd.y, iqd.z, iqd.w};

        floatx4 Em[2][3];
        #pragma unroll
        for (int tb = 0; tb < 3; ++tb) {
            const float2 in2 = *(const float2*)(input + bn * 96 + (16 * tb + r) * 2);
            float f[8];
            #pragma unroll
            for (int j = 0; j < 8; ++j) f[j] = in2.x * iq0[j] + in2.y * iq1[j];
            half8 qb = mk8(pk2(f[0], f[1]), pk2(f[2], f[3]), pk2(f[4], f[5]), pk2(f[6], f[7]));
            Em[0][tb] = __builtin_amdgcn_mfma_f32_16x16x32_f16(memA0, qb, (floatx4)0.f, 0, 0, 0);
            Em[1][tb] = __builtin_amdgcn_mfma_f32_16x16x32_f16(memA1, qb, (floatx4)0.f, 0, 0, 0);
        }
        #pragma unroll
        for (int tb = 0; tb < 3; ++tb) {
            float mx = Em[0][tb][0];
            #pragma unroll
            for (int rr = 1; rr < 4; ++rr) mx = fmaxf(mx, Em[0][tb][rr]);
            #pragma unroll
            for (int rr = 0; rr < 4; ++rr) mx = fmaxf(mx, Em[1][tb][rr]);
            mx = fmaxf(mx, __shfl_xor(mx, 16));
            mx = fmaxf(mx, __shfl_xor(mx, 32));
            uint pA0[2], pA1[2];
            #pragma unroll
            for (int d = 0; d < 2; ++d) {
                pA0[d] = pk2(__expf(Em[0][tb][2 * d] - mx), __expf(Em[0][tb][2 * d + 1] - mx));
                pA1[d] = pk2(__expf(Em[1][tb][2 * d] - mx), __expf(Em[1][tb][2 * d + 1] - mx));
            }
            half8 pA = regroup2(pA0, pA1, laneA, hiT);
            floatx4 m0 = __builtin_amdgcn_mfma_f32_16x16x32_f16(pA, memB0, (floatx4)0.f, 0, 0, 0);
            floatx4 m1 = __builtin_amdgcn_mfma_f32_16x16x32_f16(pA, memB1, (floatx4)0.f, 0, 0, 0);
            #pragma unroll
            for (int rr = 0; rr < 4; ++rr) {
                float nm = m0[rr] * m0[rr] + m1[rr] * m1[rr];
                nm += __shfl_xor(nm, 1);
                nm += __shfl_xor(nm, 2);
                nm += __shfl_xor(nm, 4);
                nm += __shfl_xor(nm, 8);
                nm_[tb][rr] = nm;            // butterfly: valid in all lanes
            }
            #pragma unroll
            for (int d = 0; d < 2; ++d) {
                mems_pk[tb][0][d] = pk2(m0[2 * d], m0[2 * d + 1]);
                mems_pk[tb][1][d] = pk2(m1[2 * d], m1[2 * d + 1]);
            }
        }
    }

    // ================= expert loop ==========================================
    #pragma unroll 1
    for (int e = 0; e < 3; ++e) {
        const float* hp = (e == 0) ? h0 : (e == 1 ? h1 : h2);
        const float* hb = hp + bn * (size_t)(TT * HID);

        // h A-frags (pkrtz casts)
        half8 Ah[3][2];
        #pragma unroll
        for (int tb = 0; tb < 3; ++tb)
            #pragma unroll
            for (int kk = 0; kk < 2; ++kk) {
                const float* src = hb + (tb * 16 + r) * HID + kk * 32 + g * 8;
                float4 x0 = *(const float4*)src;
                float4 x1 = *(const float4*)(src + 4);
                Ah[tb][kk] = mk8(pk2(x0.x, x0.y), pk2(x0.z, x0.w),
                                 pk2(x1.x, x1.y), pk2(x1.z, x1.w));
            }

        // E' via G^T = M^T h^T (nb-outer: Gacc only 2 tiles live)
        floatx4 E[3][3];
        #pragma unroll
        for (int tb = 0; tb < 3; ++tb)
            #pragma unroll
            for (int nb = 0; nb < 3; ++nb) E[tb][nb] = (floatx4)0.f;

        #pragma unroll
        for (int kk = 0; kk < 2; ++kk)
            #pragma unroll
            for (int nb = 0; nb < 3; ++nb) {
                floatx4 Ga[2] = {(floatx4)0.f, (floatx4)0.f};
                #pragma unroll
                for (int tbL = 0; tbL < 2; ++tbL) {
                    const int tbG = kk * 2 + tbL;
                    #pragma unroll
                    for (int ak = 0; ak < 2; ++ak) {
                        half8 Mhi = *(const half8*)(ws + WS_M +
                            (size_t)((((e * 2 + 0) * 4 + tbG) * 2 + ak) * 64 + lane) * 8);
                        Ga[tbL] = __builtin_amdgcn_mfma_f32_16x16x32_f16(Mhi, Ah[nb][ak], Ga[tbL], 0, 0, 0);
                    }
                }
                uint p0[2], p1[2];
                #pragma unroll
                for (int d = 0; d < 2; ++d) {
                    p0[d] = pk2(Ga[0][2 * d], Ga[0][2 * d + 1]);
                    p1[d] = pk2(Ga[1][2 * d], Ga[1][2 * d + 1]);
                }
                half8 Bh = regroup2(p0, p1, laneA, hiT);
                #pragma unroll
                for (int tb = 0; tb < 3; ++tb)
                    E[tb][nb] = __builtin_amdgcn_mfma_f32_16x16x32_f16(Ah[tb][kk], Bh, E[tb][nb], 0, 0, 0);
            }

        // softmax numerators over s
        #pragma unroll
        for (int nb = 0; nb < 3; ++nb) {
            float m = E[0][nb][0];
            #pragma unroll
            for (int tb = 0; tb < 3; ++tb)
                #pragma unroll
                for (int rr = 0; rr < 4; ++rr) m = fmaxf(m, E[tb][nb][rr]);
            m = fmaxf(m, __shfl_xor(m, 16));
            m = fmaxf(m, __shfl_xor(m, 32));
            #pragma unroll
            for (int tb = 0; tb < 3; ++tb)
                #pragma unroll
                for (int rr = 0; rr < 4; ++rr) E[tb][nb][rr] = __expf(E[tb][nb][rr] - m);
        }

        // P'^T A-frags
        half8 PF[3][2];
        #pragma unroll
        for (int tbT = 0; tbT < 3; ++tbT) {
            uint pk[3][2];
            #pragma unroll
            for (int t = 0; t < 3; ++t)
                #pragma unroll
                for (int d = 0; d < 2; ++d)
                    pk[t][d] = pk2(E[t][tbT][2 * d], E[t][tbT][2 * d + 1]);
            PF[tbT][0] = regroup2(pk[0], pk[1], laneA, hiT);
            PF[tbT][1] = regroup1pad(pk[2], laneA, hiT);
        }

        // v projection + regroup to PV B-frags
        half8 vb[2][2];
        {
            half8 WV[2][2];
            #pragma unroll
            for (int kk = 0; kk < 2; ++kk)
                #pragma unroll
                for (int nb = 0; nb < 2; ++nb)
                    WV[kk][nb] = *(const half8*)(ws + WS_WV + e * 2048 + (size_t)((kk * 2 + nb) * 64 + lane) * 8);
            floatx4 vacc[3][2];
            #pragma unroll
            for (int tb = 0; tb < 3; ++tb) { vacc[tb][0] = (floatx4)0.f; vacc[tb][1] = (floatx4)0.f; }
            #pragma unroll
            for (int kk = 0; kk < 2; ++kk)
                #pragma unroll
                for (int tb = 0; tb < 3; ++tb)
                    #pragma unroll
                    for (int nb = 0; nb < 2; ++nb)
                        vacc[tb][nb] = __builtin_amdgcn_mfma_f32_16x16x32_f16(Ah[tb][kk], WV[kk][nb], vacc[tb][nb], 0, 0, 0);
            #pragma unroll
            for (int nb = 0; nb < 2; ++nb) {
                uint pkv[3][2];
                #pragma unroll
                for (int tb = 0; tb < 3; ++tb)
                    #pragma unroll
                    for (int d = 0; d < 2; ++d)
                        pkv[tb][d] = pk2(vacc[tb][nb][2 * d], vacc[tb][nb][2 * d + 1]);
                vb[nb][0] = regroup2(pkv[0], pkv[1], laneA, hiT);
                vb[nb][1] = regroup1pad(pkv[2], laneA, hiT);
            }
        }

        // att = P'^T @ v
        floatx4 att[3][2];
        #pragma unroll
        for (int tb = 0; tb < 3; ++tb) { att[tb][0] = (floatx4)0.f; att[tb][1] = (floatx4)0.f; }
        #pragma unroll
        for (int kk = 0; kk < 2; ++kk)
            #pragma unroll
            for (int tb = 0; tb < 3; ++tb) {
                att[tb][0] = __builtin_amdgcn_mfma_f32_16x16x32_f16(PF[tb][kk], vb[0][kk], att[tb][0], 0, 0, 0);
                att[tb][1] = __builtin_amdgcn_mfma_f32_16x16x32_f16(PF[tb][kk], vb[1][kk], att[tb][1], 0, 0, 0);
            }

        // cosine vs packed memories: (nu,nr) packed f16, scale 1/64; nm precomputed
        #pragma unroll
        for (int tb = 0; tb < 3; ++tb)
            #pragma unroll
            for (int rr = 0; rr < 4; ++rr) {
                int t = 16 * tb + 4 * g + rr;
                float a0 = att[tb][0][rr], a1 = att[tb][1][rr];
                float m0 = (rr & 1) ? f16hi(mems_pk[tb][0][rr >> 1]) : f16lo(mems_pk[tb][0][rr >> 1]);
                float m1 = (rr & 1) ? f16hi(mems_pk[tb][1][rr >> 1]) : f16lo(mems_pk[tb][1][rr >> 1]);
                float nu = a0 * m0 + a1 * m1;
                float nr = a0 * a0 + a1 * a1;
                uint nur = pk2(nu * 0.015625f, nr * 0.015625f);
                nur = pkadd(nur, (uint)__shfl_xor((int)nur, 1));
                nur = pkadd(nur, (uint)__shfl_xor((int)nur, 2));
                nur = pkadd(nur, (uint)__shfl_xor((int)nur, 4));
                nur = pkadd(nur, (uint)__shfl_xor((int)nur, 8));
                if (r == 0) {
                    float nuv = f16lo(nur), nrv = f16hi(nur);
                    float den = fmaxf(8.f * sqrtf(nrv * nm_[tb][rr]), 1e-8f);
                    out[(bn * TT + t) * 3 + e] = 64.f * nuv / den;
                }
            }
    }
}

extern "C" void kernel_launch(void* const* d_in, const int* in_sizes, int n_in,
                              void* d_out, int out_size, void* d_ws, size_t ws_size,
                              hipStream_t stream) {
    const float* input       = (const float*)d_in[0];
    const float* h0          = (const float*)d_in[1];
    const float* h1          = (const float*)d_in[2];
    const float* h2          = (const float*)d_in[3];
    const float* memory      = (const float*)d_in[4];
    const float* input_query = (const float*)d_in[5];
    const float* hid_query   = (const float*)d_in[6];
    const float* key_w       = (const float*)d_in[7];
    const float* value_w     = (const float*)d_in[8];
    float* out = (float*)d_out;
    _Float16* ws = (_Float16*)d_ws;   // 65536 bytes used

    hipLaunchKernelGGL(prep_frags, dim3(3), dim3(256), 0, stream,
                       hid_query, key_w, value_w, memory, ws);
    hipLaunchKernelGGL(testam_wave, dim3(16 * 1024 / NWAVES), dim3(256), 0, stream,
                       input, h0, h1, h2, input_query, ws, out);
}

// Round 11
// 213.151 us; speedup vs baseline: 1.1671x; 1.1671x over previous
//
#include <hip/hip_runtime.h>

typedef _Float16 half8 __attribute__((ext_vector_type(8)));
typedef __fp16 fp16x2 __attribute__((ext_vector_type(2)));
typedef float floatx4 __attribute__((ext_vector_type(4)));
typedef unsigned int uint;
typedef uint uint4t __attribute__((ext_vector_type(4)));

namespace {
constexpr int TT = 48, HID = 64, MH = 32, MS = 20;
constexpr int NWAVES = 4;         // waves per block (independent bn)
// d_ws offsets in half elements (total 32768 halves = 64 KiB)
constexpr int WS_WV   = 0;        // value_w B-frags: [e][kk][nb] * 512
constexpr int WS_MEMA = 6144;     // mem A-frags (rows s, zero s>=20): 1024
constexpr int WS_MEMB = 7168;     // mem B-frags (k=s, col m, zero s>=20): 1024
constexpr int WS_M    = 8192;     // M^T A-frags: [e][hl][tbG][ak] * 512 (hl=1 unused)
}

static __device__ inline uint pk2(float a, float b) {
    fp16x2 h = __builtin_amdgcn_cvt_pkrtz(a, b);
    return __builtin_bit_cast(uint, h);
}
static __device__ inline half8 mk8(uint a, uint b, uint c, uint d) {
    uint4t u = {a, b, c, d};
    return __builtin_bit_cast(half8, u);
}
static __device__ inline uint pkadd(uint a, uint b) {
    fp16x2 x = __builtin_bit_cast(fp16x2, a);
    fp16x2 y = __builtin_bit_cast(fp16x2, b);
    fp16x2 z = x + y;                      // v_pk_add_f16
    return __builtin_bit_cast(uint, z);
}
static __device__ inline uint pkmax(uint a, uint b) {
    fp16x2 x = __builtin_bit_cast(fp16x2, a);
    fp16x2 y = __builtin_bit_cast(fp16x2, b);
    fp16x2 z = __builtin_elementwise_max(x, y);   // v_pk_max_f16
    return __builtin_bit_cast(uint, z);
}
static __device__ inline float f16lo(uint u) {
    fp16x2 f = __builtin_bit_cast(fp16x2, u); return (float)f[0];
}
static __device__ inline float f16hi(uint u) {
    fp16x2 f = __builtin_bit_cast(fp16x2, u); return (float)f[1];
}
// C-layout -> fragment regroup (verified rounds 6-10)
static __device__ inline half8 regroup2(const uint p0[2], const uint p1[2],
                                        int laneA, bool hiT) {
    uint w[4];
    #pragma unroll
    for (int d = 0; d < 2; ++d) {
        int a0 = __shfl((int)p0[d], laneA);
        int a1 = __shfl((int)p1[d], laneA);
        int b0 = __shfl((int)p0[d], laneA + 16);
        int b1 = __shfl((int)p1[d], laneA + 16);
        w[d]     = hiT ? (uint)a1 : (uint)a0;
        w[2 + d] = hiT ? (uint)b1 : (uint)b0;
    }
    return mk8(w[0], w[1], w[2], w[3]);
}
static __device__ inline half8 regroup1pad(const uint p2[2], int laneA, bool hiT) {
    uint w[4];
    #pragma unroll
    for (int d = 0; d < 2; ++d) {
        int a2 = __shfl((int)p2[d], laneA);
        int b2 = __shfl((int)p2[d], laneA + 16);
        w[d]     = hiT ? 0u : (uint)a2;
        w[2 + d] = hiT ? 0u : (uint)b2;
    }
    return mk8(w[0], w[1], w[2], w[3]);
}

// Prep: per-expert M = Wq*Wk^T (fp32) -> M^T A-frags; value_w B-frags; mem frags.
__global__ __launch_bounds__(256)
void prep_frags(const float* __restrict__ hid_query,
                const float* __restrict__ key_w,
                const float* __restrict__ value_w,
                const float* __restrict__ memory,
                _Float16* __restrict__ ws)
{
    const int e = blockIdx.x, tid = threadIdx.x;
    __shared__ float sWq[HID * MH], sWk[HID * MH], sM[HID * HID];
    for (int i = tid; i < HID * MH; i += 256) {
        sWq[i] = hid_query[e * HID * MH + i];
        sWk[i] = key_w[e * HID * MH + i];
    }
    __syncthreads();
    for (int i = tid; i < HID * HID; i += 256) {
        int a = i >> 6, b = i & 63;
        float acc = 0.f;
        #pragma unroll
        for (int m = 0; m < MH; ++m) acc = fmaf(sWq[a * MH + m], sWk[b * MH + m], acc);
        sM[i] = acc;
    }
    __syncthreads();
    for (int i = tid; i < 16 * 512; i += 256) {
        int j = i & 7, lane = (i >> 3) & 63, ak = (i >> 9) & 1, tbG = (i >> 10) & 3, hl = (i >> 12) & 1;
        float v = sM[(32 * ak + 8 * (lane >> 4) + j) * 64 + 16 * tbG + (lane & 15)];
        _Float16 hi = (_Float16)v;
        ws[WS_M + (size_t)((((e * 2 + hl) * 4 + tbG) * 2 + ak) << 9) + (i & 511)] =
            hl ? (_Float16)(v - (float)hi) : hi;
    }
    for (int i = tid; i < 2048; i += 256) {
        int j = i & 7, lane = (i >> 3) & 63, nb = (i >> 9) & 1, kk = (i >> 10) & 1;
        int h = kk * 32 + (lane >> 4) * 8 + j;
        int m = nb * 16 + (lane & 15);
        ws[WS_WV + e * 2048 + (i & 2047)] = (_Float16)value_w[((size_t)e * HID + h) * MH + m];
    }
    if (e == 0) {
        for (int i = tid; i < 1024; i += 256) {
            int j = i & 7, lane = (i >> 3) & 63, sb = i >> 9;
            int s = 16 * sb + (lane & 15);
            int m = (lane >> 4) * 8 + j;
            ws[WS_MEMA + i] = (s < MS) ? (_Float16)memory[s * MH + m] : (_Float16)0.f;
        }
        for (int i = tid; i < 1024; i += 256) {
            int j = i & 7, lane = (i >> 3) & 63, nb = i >> 9;
            int s = (lane >> 4) * 8 + j;
            int m = 16 * nb + (lane & 15);
            ws[WS_MEMB + i] = (s < MS) ? (_Float16)memory[s * MH + m] : (_Float16)0.f;
        }
    }
}

// One wave per bn, e-loop inside (phase A once per bn). No LDS. Register-dieted.
__global__ __launch_bounds__(256, 4)
void testam_wave(const float* __restrict__ input,
                 const float* __restrict__ h0,
                 const float* __restrict__ h1,
                 const float* __restrict__ h2,
                 const float* __restrict__ input_query,
                 const _Float16* __restrict__ ws,
                 float* __restrict__ out)
{
    const int tid  = threadIdx.x;
    const int wid  = tid >> 6;
    const int lane = tid & 63;
    const int r = lane & 15, g = lane >> 4;
    const size_t bn = (size_t)blockIdx.x * NWAVES + wid;

    const int laneA = (g & 1) * 32 + r;
    const bool hiT = (g >= 2);

    // ================= phase A (once per bn): memories + norms ==============
    uint  mems_pk[3][2][2];   // memories, f16-packed, C-layout pairs
    float nm_[3][4];          // |memories|^2 per t, reduced, valid in ALL lanes
    {
        half8 memA0 = *(const half8*)(ws + WS_MEMA + (size_t)lane * 8);
        half8 memA1 = *(const half8*)(ws + WS_MEMA + (size_t)(64 + lane) * 8);
        half8 memB0 = *(const half8*)(ws + WS_MEMB + (size_t)lane * 8);
        half8 memB1 = *(const half8*)(ws + WS_MEMB + (size_t)(64 + lane) * 8);

        float4 iqa = *(const float4*)(input_query + g * 8);
        float4 iqb = *(const float4*)(input_query + g * 8 + 4);
        float4 iqc = *(const float4*)(input_query + 32 + g * 8);
        float4 iqd = *(const float4*)(input_query + 32 + g * 8 + 4);
        float iq0[8] = {iqa.x, iqa.y, iqa.z, iqa.w, iqb.x, iqb.y, iqb.z, iqb.w};
        float iq1[8] = {iqc.x, iqc.y, iqc.z, iqc.w, iqd.x, iqd.y, iqd.z, iqd.w};

        floatx4 Em[2][3];
        #pragma unroll
        for (int tb = 0; tb < 3; ++tb) {
            const float2 in2 = *(const float2*)(input + bn * 96 + (16 * tb + r) * 2);
            float f[8];
            #pragma unroll
            for (int j = 0; j < 8; ++j) f[j] = in2.x * iq0[j] + in2.y * iq1[j];
            half8 qb = mk8(pk2(f[0], f[1]), pk2(f[2], f[3]), pk2(f[4], f[5]), pk2(f[6], f[7]));
            Em[0][tb] = __builtin_amdgcn_mfma_f32_16x16x32_f16(memA0, qb, (floatx4)0.f, 0, 0, 0);
            Em[1][tb] = __builtin_amdgcn_mfma_f32_16x16x32_f16(memA1, qb, (floatx4)0.f, 0, 0, 0);
        }
        #pragma unroll
        for (int tb = 0; tb < 3; ++tb) {
            float mx = Em[0][tb][0];
            #pragma unroll
            for (int rr = 1; rr < 4; ++rr) mx = fmaxf(mx, Em[0][tb][rr]);
            #pragma unroll
            for (int rr = 0; rr < 4; ++rr) mx = fmaxf(mx, Em[1][tb][rr]);
            mx = fmaxf(mx, __shfl_xor(mx, 16));
            mx = fmaxf(mx, __shfl_xor(mx, 32));
            uint pA0[2], pA1[2];
            #pragma unroll
            for (int d = 0; d < 2; ++d) {
                pA0[d] = pk2(__expf(Em[0][tb][2 * d] - mx), __expf(Em[0][tb][2 * d + 1] - mx));
                pA1[d] = pk2(__expf(Em[1][tb][2 * d] - mx), __expf(Em[1][tb][2 * d + 1] - mx));
            }
            half8 pA = regroup2(pA0, pA1, laneA, hiT);
            floatx4 m0 = __builtin_amdgcn_mfma_f32_16x16x32_f16(pA, memB0, (floatx4)0.f, 0, 0, 0);
            floatx4 m1 = __builtin_amdgcn_mfma_f32_16x16x32_f16(pA, memB1, (floatx4)0.f, 0, 0, 0);
            #pragma unroll
            for (int rr = 0; rr < 4; ++rr) {
                float nm = m0[rr] * m0[rr] + m1[rr] * m1[rr];
                nm += __shfl_xor(nm, 1);
                nm += __shfl_xor(nm, 2);
                nm += __shfl_xor(nm, 4);
                nm += __shfl_xor(nm, 8);
                nm_[tb][rr] = nm;            // butterfly: valid in all lanes
            }
            #pragma unroll
            for (int d = 0; d < 2; ++d) {
                mems_pk[tb][0][d] = pk2(m0[2 * d], m0[2 * d + 1]);
                mems_pk[tb][1][d] = pk2(m1[2 * d], m1[2 * d + 1]);
            }
        }
    }

    // ================= expert loop ==========================================
    #pragma unroll 1
    for (int e = 0; e < 3; ++e) {
        const float* hp = (e == 0) ? h0 : (e == 1 ? h1 : h2);
        const float* hb = hp + bn * (size_t)(TT * HID);

        // h A-frags (pkrtz casts)
        half8 Ah[3][2];
        #pragma unroll
        for (int tb = 0; tb < 3; ++tb)
            #pragma unroll
            for (int kk = 0; kk < 2; ++kk) {
                const float* src = hb + (tb * 16 + r) * HID + kk * 32 + g * 8;
                float4 x0 = *(const float4*)src;
                float4 x1 = *(const float4*)(src + 4);
                Ah[tb][kk] = mk8(pk2(x0.x, x0.y), pk2(x0.z, x0.w),
                                 pk2(x1.x, x1.y), pk2(x1.z, x1.w));
            }

        // Bh for both kk (G^T = M^T h^T, M-frags reused across nb)
        half8 Bh[2][3];
        #pragma unroll
        for (int kk = 0; kk < 2; ++kk) {
            floatx4 Ga[2][3];   // [tbL][nb]
            #pragma unroll
            for (int t = 0; t < 2; ++t)
                #pragma unroll
                for (int nb = 0; nb < 3; ++nb) Ga[t][nb] = (floatx4)0.f;
            #pragma unroll
            for (int tbL = 0; tbL < 2; ++tbL) {
                const int tbG = kk * 2 + tbL;
                #pragma unroll
                for (int ak = 0; ak < 2; ++ak) {
                    half8 Mhi = *(const half8*)(ws + WS_M +
                        (size_t)((((e * 2 + 0) * 4 + tbG) * 2 + ak) * 64 + lane) * 8);
                    #pragma unroll
                    for (int nb = 0; nb < 3; ++nb)
                        Ga[tbL][nb] = __builtin_amdgcn_mfma_f32_16x16x32_f16(Mhi, Ah[nb][ak], Ga[tbL][nb], 0, 0, 0);
                }
            }
            #pragma unroll
            for (int nb = 0; nb < 3; ++nb) {
                uint p0[2], p1[2];
                #pragma unroll
                for (int d = 0; d < 2; ++d) {
                    p0[d] = pk2(Ga[0][nb][2 * d], Ga[0][nb][2 * d + 1]);
                    p1[d] = pk2(Ga[1][nb][2 * d], Ga[1][nb][2 * d + 1]);
                }
                Bh[kk][nb] = regroup2(p0, p1, laneA, hiT);
            }
        }

        // E' chained over kk, packed to f16 immediately (18 regs, not 36)
        uint E_pk[3][3][2];
        #pragma unroll
        for (int nb = 0; nb < 3; ++nb)
            #pragma unroll
            for (int tb = 0; tb < 3; ++tb) {
                floatx4 a = __builtin_amdgcn_mfma_f32_16x16x32_f16(Ah[tb][0], Bh[0][nb], (floatx4)0.f, 0, 0, 0);
                a = __builtin_amdgcn_mfma_f32_16x16x32_f16(Ah[tb][1], Bh[1][nb], a, 0, 0, 0);
                E_pk[tb][nb][0] = pk2(a[0], a[1]);
                E_pk[tb][nb][1] = pk2(a[2], a[3]);
            }

        // v projection (last use of Ah) + regroup to PV B-frags
        half8 vb[2][2];
        {
            half8 WV[2][2];
            #pragma unroll
            for (int kk = 0; kk < 2; ++kk)
                #pragma unroll
                for (int nb = 0; nb < 2; ++nb)
                    WV[kk][nb] = *(const half8*)(ws + WS_WV + e * 2048 + (size_t)((kk * 2 + nb) * 64 + lane) * 8);
            floatx4 vacc[3][2];
            #pragma unroll
            for (int tb = 0; tb < 3; ++tb) { vacc[tb][0] = (floatx4)0.f; vacc[tb][1] = (floatx4)0.f; }
            #pragma unroll
            for (int kk = 0; kk < 2; ++kk)
                #pragma unroll
                for (int tb = 0; tb < 3; ++tb)
                    #pragma unroll
                    for (int nb = 0; nb < 2; ++nb)
                        vacc[tb][nb] = __builtin_amdgcn_mfma_f32_16x16x32_f16(Ah[tb][kk], WV[kk][nb], vacc[tb][nb], 0, 0, 0);
            #pragma unroll
            for (int nb = 0; nb < 2; ++nb) {
                uint pkv[3][2];
                #pragma unroll
                for (int tb = 0; tb < 3; ++tb)
                    #pragma unroll
                    for (int d = 0; d < 2; ++d)
                        pkv[tb][d] = pk2(vacc[tb][nb][2 * d], vacc[tb][nb][2 * d + 1]);
                vb[nb][0] = regroup2(pkv[0], pkv[1], laneA, hiT);
                vb[nb][1] = regroup1pad(pkv[2], laneA, hiT);
            }
        }

        // softmax (max via v_pk_max_f16 on packed E) + P'^T A-frags
        half8 PF[3][2];
        #pragma unroll
        for (int nb = 0; nb < 3; ++nb) {
            uint mp = pkmax(E_pk[0][nb][0], E_pk[0][nb][1]);
            mp = pkmax(mp, pkmax(E_pk[1][nb][0], E_pk[1][nb][1]));
            mp = pkmax(mp, pkmax(E_pk[2][nb][0], E_pk[2][nb][1]));
            float m = fmaxf(f16lo(mp), f16hi(mp));
            m = fmaxf(m, __shfl_xor(m, 16));
            m = fmaxf(m, __shfl_xor(m, 32));
            uint pk[3][2];
            #pragma unroll
            for (int t = 0; t < 3; ++t)
                #pragma unroll
                for (int d = 0; d < 2; ++d)
                    pk[t][d] = pk2(__expf(f16lo(E_pk[t][nb][d]) - m),
                                   __expf(f16hi(E_pk[t][nb][d]) - m));
            PF[nb][0] = regroup2(pk[0], pk[1], laneA, hiT);
            PF[nb][1] = regroup1pad(pk[2], laneA, hiT);
        }

        // att = P'^T @ v
        floatx4 att[3][2];
        #pragma unroll
        for (int tb = 0; tb < 3; ++tb) { att[tb][0] = (floatx4)0.f; att[tb][1] = (floatx4)0.f; }
        #pragma unroll
        for (int kk = 0; kk < 2; ++kk)
            #pragma unroll
            for (int tb = 0; tb < 3; ++tb) {
                att[tb][0] = __builtin_amdgcn_mfma_f32_16x16x32_f16(PF[tb][kk], vb[0][kk], att[tb][0], 0, 0, 0);
                att[tb][1] = __builtin_amdgcn_mfma_f32_16x16x32_f16(PF[tb][kk], vb[1][kk], att[tb][1], 0, 0, 0);
            }

        // cosine vs packed memories: (nu,nr) packed f16, scale 1/64; nm precomputed
        #pragma unroll
        for (int tb = 0; tb < 3; ++tb)
            #pragma unroll
            for (int rr = 0; rr < 4; ++rr) {
                int t = 16 * tb + 4 * g + rr;
                float a0 = att[tb][0][rr], a1 = att[tb][1][rr];
                float m0 = (rr & 1) ? f16hi(mems_pk[tb][0][rr >> 1]) : f16lo(mems_pk[tb][0][rr >> 1]);
                float m1 = (rr & 1) ? f16hi(mems_pk[tb][1][rr >> 1]) : f16lo(mems_pk[tb][1][rr >> 1]);
                float nu = a0 * m0 + a1 * m1;
                float nr = a0 * a0 + a1 * a1;
                uint nur = pk2(nu * 0.015625f, nr * 0.015625f);
                nur = pkadd(nur, (uint)__shfl_xor((int)nur, 1));
                nur = pkadd(nur, (uint)__shfl_xor((int)nur, 2));
                nur = pkadd(nur, (uint)__shfl_xor((int)nur, 4));
                nur = pkadd(nur, (uint)__shfl_xor((int)nur, 8));
                if (r == 0) {
                    float nuv = f16lo(nur), nrv = f16hi(nur);
                    float den = fmaxf(8.f * sqrtf(nrv * nm_[tb][rr]), 1e-8f);
                    out[(bn * TT + t) * 3 + e] = 64.f * nuv / den;
                }
            }
    }
}

extern "C" void kernel_launch(void* const* d_in, const int* in_sizes, int n_in,
                              void* d_out, int out_size, void* d_ws, size_t ws_size,
                              hipStream_t stream) {
    const float* input       = (const float*)d_in[0];
    const float* h0          = (const float*)d_in[1];
    const float* h1          = (const float*)d_in[2];
    const float* h2          = (const float*)d_in[3];
    const float* memory      = (const float*)d_in[4];
    const float* input_query = (const float*)d_in[5];
    const float* hid_query   = (const float*)d_in[6];
    const float* key_w       = (const float*)d_in[7];
    const float* value_w     = (const float*)d_in[8];
    float* out = (float*)d_out;
    _Float16* ws = (_Float16*)d_ws;   // 65536 bytes used

    hipLaunchKernelGGL(prep_frags, dim3(3), dim3(256), 0, stream,
                       hid_query, key_w, value_w, memory, ws);
    hipLaunchKernelGGL(testam_wave, dim3(16 * 1024 / NWAVES), dim3(256), 0, stream,
                       input, h0, h1, h2, input_query, ws, out);
}

// Round 12
// 194.514 us; speedup vs baseline: 1.2789x; 1.0958x over previous
//
#include <hip/hip_runtime.h>

typedef _Float16 half8 __attribute__((ext_vector_type(8)));
typedef __fp16 fp16x2 __attribute__((ext_vector_type(2)));
typedef float floatx4 __attribute__((ext_vector_type(4)));
typedef unsigned int uint;
typedef uint uint4t __attribute__((ext_vector_type(4)));

namespace {
constexpr int TT = 48, HID = 64, MH = 32, MS = 20;
// d_ws offsets in half elements (total 32768 halves = 64 KiB)
constexpr int WS_WV   = 0;        // value_w B-frags: [e][kk][nb] * 512
constexpr int WS_MEMA = 6144;     // mem A-frags (rows s, zero s>=20): 1024
constexpr int WS_MEMB = 7168;     // mem B-frags (k=s, col m, zero s>=20): 1024
constexpr int WS_M    = 8192;     // M^T A-frags: [e][hl][tbG][ak] * 512 (hl=1 unused)
}

static __device__ inline uint pk2(float a, float b) {
    fp16x2 h = __builtin_amdgcn_cvt_pkrtz(a, b);
    return __builtin_bit_cast(uint, h);
}
static __device__ inline half8 mk8(uint a, uint b, uint c, uint d) {
    uint4t u = {a, b, c, d};
    return __builtin_bit_cast(half8, u);
}
static __device__ inline uint pkadd(uint a, uint b) {
    fp16x2 x = __builtin_bit_cast(fp16x2, a);
    fp16x2 y = __builtin_bit_cast(fp16x2, b);
    fp16x2 z = x + y;                      // v_pk_add_f16
    return __builtin_bit_cast(uint, z);
}
static __device__ inline float f16lo(uint u) {
    fp16x2 f = __builtin_bit_cast(fp16x2, u); return (float)f[0];
}
static __device__ inline float f16hi(uint u) {
    fp16x2 f = __builtin_bit_cast(fp16x2, u); return (float)f[1];
}
// DPP lane-permute (within 16-lane rows): 0xB1=xor1, 0x4E=xor2, 0x124=ror4, 0x128=ror8
template<int CTRL>
static __device__ inline uint dpp_mov(uint x) {
    return (uint)__builtin_amdgcn_update_dpp(0, (int)x, CTRL, 0xF, 0xF, true);
}
// full 16-lane f16x2 sum; result valid in all 16 lanes of each row
static __device__ inline uint dpp_reduce_pk(uint v) {
    v = pkadd(v, dpp_mov<0x128>(v));   // +ror8
    v = pkadd(v, dpp_mov<0x124>(v));   // +ror4
    v = pkadd(v, dpp_mov<0x4E>(v));    // +xor2
    v = pkadd(v, dpp_mov<0xB1>(v));    // +xor1
    return v;
}
static __device__ inline float dpp_reduce_f32(float v) {
    #define STEP(C) { int t = __builtin_amdgcn_update_dpp(0, __builtin_bit_cast(int, v), C, 0xF, 0xF, true); \
                      v += __builtin_bit_cast(float, t); }
    STEP(0x128) STEP(0x124) STEP(0x4E) STEP(0xB1)
    #undef STEP
    return v;
}
// C-layout -> fragment regroup (verified rounds 6-11)
static __device__ inline half8 regroup2(const uint p0[2], const uint p1[2],
                                        int laneA, bool hiT) {
    uint w[4];
    #pragma unroll
    for (int d = 0; d < 2; ++d) {
        int a0 = __shfl((int)p0[d], laneA);
        int a1 = __shfl((int)p1[d], laneA);
        int b0 = __shfl((int)p0[d], laneA + 16);
        int b1 = __shfl((int)p1[d], laneA + 16);
        w[d]     = hiT ? (uint)a1 : (uint)a0;
        w[2 + d] = hiT ? (uint)b1 : (uint)b0;
    }
    return mk8(w[0], w[1], w[2], w[3]);
}
static __device__ inline half8 regroup1pad(const uint p2[2], int laneA, bool hiT) {
    uint w[4];
    #pragma unroll
    for (int d = 0; d < 2; ++d) {
        int a2 = __shfl((int)p2[d], laneA);
        int b2 = __shfl((int)p2[d], laneA + 16);
        w[d]     = hiT ? 0u : (uint)a2;
        w[2 + d] = hiT ? 0u : (uint)b2;
    }
    return mk8(w[0], w[1], w[2], w[3]);
}

// Prep: per-expert M = Wq*Wk^T (fp32) -> M^T A-frags; value_w B-frags; mem frags.
__global__ __launch_bounds__(256)
void prep_frags(const float* __restrict__ hid_query,
                const float* __restrict__ key_w,
                const float* __restrict__ value_w,
                const float* __restrict__ memory,
                _Float16* __restrict__ ws)
{
    const int e = blockIdx.x, tid = threadIdx.x;
    __shared__ float sWq[HID * MH], sWk[HID * MH], sM[HID * HID];
    for (int i = tid; i < HID * MH; i += 256) {
        sWq[i] = hid_query[e * HID * MH + i];
        sWk[i] = key_w[e * HID * MH + i];
    }
    __syncthreads();
    for (int i = tid; i < HID * HID; i += 256) {
        int a = i >> 6, b = i & 63;
        float acc = 0.f;
        #pragma unroll
        for (int m = 0; m < MH; ++m) acc = fmaf(sWq[a * MH + m], sWk[b * MH + m], acc);
        sM[i] = acc;
    }
    __syncthreads();
    for (int i = tid; i < 16 * 512; i += 256) {
        int j = i & 7, lane = (i >> 3) & 63, ak = (i >> 9) & 1, tbG = (i >> 10) & 3, hl = (i >> 12) & 1;
        float v = sM[(32 * ak + 8 * (lane >> 4) + j) * 64 + 16 * tbG + (lane & 15)];
        _Float16 hi = (_Float16)v;
        ws[WS_M + (size_t)((((e * 2 + hl) * 4 + tbG) * 2 + ak) << 9) + (i & 511)] =
            hl ? (_Float16)(v - (float)hi) : hi;
    }
    for (int i = tid; i < 2048; i += 256) {
        int j = i & 7, lane = (i >> 3) & 63, nb = (i >> 9) & 1, kk = (i >> 10) & 1;
        int h = kk * 32 + (lane >> 4) * 8 + j;
        int m = nb * 16 + (lane & 15);
        ws[WS_WV + e * 2048 + (i & 2047)] = (_Float16)value_w[((size_t)e * HID + h) * MH + m];
    }
    if (e == 0) {
        for (int i = tid; i < 1024; i += 256) {
            int j = i & 7, lane = (i >> 3) & 63, sb = i >> 9;
            int s = 16 * sb + (lane & 15);
            int m = (lane >> 4) * 8 + j;
            ws[WS_MEMA + i] = (s < MS) ? (_Float16)memory[s * MH + m] : (_Float16)0.f;
        }
        for (int i = tid; i < 1024; i += 256) {
            int j = i & 7, lane = (i >> 3) & 63, nb = i >> 9;
            int s = (lane >> 4) * 8 + j;
            int m = 16 * nb + (lane & 15);
            ws[WS_MEMB + i] = (s < MS) ? (_Float16)memory[s * MH + m] : (_Float16)0.f;
        }
    }
}

// Block = one bn, 3 waves = 3 experts. Phase A split by tb across the 3 waves
// (once per bn total), broadcast via 3.3 KB LDS, one barrier. Expert body = r9.
__global__ __launch_bounds__(192, 4)
void testam_wave(const float* __restrict__ input,
                 const float* __restrict__ h0,
                 const float* __restrict__ h1,
                 const float* __restrict__ h2,
                 const float* __restrict__ input_query,
                 const _Float16* __restrict__ ws,
                 float* __restrict__ out)
{
    __shared__ __align__(16) uint s_mem_pk[3 * 64 * 4];   // [tb][lane][4 dwords]
    __shared__ float s_nm[TT];

    const int tid  = threadIdx.x;
    const int e    = tid >> 6;          // wave id = expert
    const int lane = tid & 63;
    const int r = lane & 15, g = lane >> 4;
    const size_t bn = blockIdx.x;

    const int laneA = (g & 1) * 32 + r;
    const bool hiT = (g >= 2);

    // ===== phase A, 1/3 per wave (tb = e): memories + norms -> LDS ==========
    {
        const int tb = e;
        half8 memA0 = *(const half8*)(ws + WS_MEMA + (size_t)lane * 8);
        half8 memA1 = *(const half8*)(ws + WS_MEMA + (size_t)(64 + lane) * 8);
        half8 memB0 = *(const half8*)(ws + WS_MEMB + (size_t)lane * 8);
        half8 memB1 = *(const half8*)(ws + WS_MEMB + (size_t)(64 + lane) * 8);

        float4 iqa = *(const float4*)(input_query + g * 8);
        float4 iqb = *(const float4*)(input_query + g * 8 + 4);
        float4 iqc = *(const float4*)(input_query + 32 + g * 8);
        float4 iqd = *(const float4*)(input_query + 32 + g * 8 + 4);
        float iq0[8] = {iqa.x, iqa.y, iqa.z, iqa.w, iqb.x, iqb.y, iqb.z, iqb.w};
        float iq1[8] = {iqc.x, iqc.y, iqc.z, iqc.w, iqd.x, iqd.y, iqd.z, iqd.w};

        const float2 in2 = *(const float2*)(input + bn * 96 + (16 * tb + r) * 2);
        float f[8];
        #pragma unroll
        for (int j = 0; j < 8; ++j) f[j] = in2.x * iq0[j] + in2.y * iq1[j];
        half8 qb = mk8(pk2(f[0], f[1]), pk2(f[2], f[3]), pk2(f[4], f[5]), pk2(f[6], f[7]));
        floatx4 Em0 = __builtin_amdgcn_mfma_f32_16x16x32_f16(memA0, qb, (floatx4)0.f, 0, 0, 0);
        floatx4 Em1 = __builtin_amdgcn_mfma_f32_16x16x32_f16(memA1, qb, (floatx4)0.f, 0, 0, 0);

        float mx = Em0[0];
        #pragma unroll
        for (int rr = 1; rr < 4; ++rr) mx = fmaxf(mx, Em0[rr]);
        #pragma unroll
        for (int rr = 0; rr < 4; ++rr) mx = fmaxf(mx, Em1[rr]);
        mx = fmaxf(mx, __shfl_xor(mx, 16));
        mx = fmaxf(mx, __shfl_xor(mx, 32));
        uint pA0[2], pA1[2];
        #pragma unroll
        for (int d = 0; d < 2; ++d) {
            pA0[d] = pk2(__expf(Em0[2 * d] - mx), __expf(Em0[2 * d + 1] - mx));
            pA1[d] = pk2(__expf(Em1[2 * d] - mx), __expf(Em1[2 * d + 1] - mx));
        }
        half8 pA = regroup2(pA0, pA1, laneA, hiT);
        floatx4 m0 = __builtin_amdgcn_mfma_f32_16x16x32_f16(pA, memB0, (floatx4)0.f, 0, 0, 0);
        floatx4 m1 = __builtin_amdgcn_mfma_f32_16x16x32_f16(pA, memB1, (floatx4)0.f, 0, 0, 0);
        #pragma unroll
        for (int rr = 0; rr < 4; ++rr) {
            float nm = dpp_reduce_f32(m0[rr] * m0[rr] + m1[rr] * m1[rr]);
            if (r == 0) s_nm[16 * tb + 4 * g + rr] = nm;
        }
        uint4t mp = { pk2(m0[0], m0[1]), pk2(m0[2], m0[3]),
                      pk2(m1[0], m1[1]), pk2(m1[2], m1[3]) };
        *(uint4t*)&s_mem_pk[(tb * 64 + lane) * 4] = mp;
    }
    __syncthreads();

    // ===== expert body (r9-proven, per wave) ================================
    const float* hp = (e == 0) ? h0 : (e == 1 ? h1 : h2);
    const float* hb = hp + bn * (size_t)(TT * HID);

    half8 Ah[3][2];
    #pragma unroll
    for (int tb = 0; tb < 3; ++tb)
        #pragma unroll
        for (int kk = 0; kk < 2; ++kk) {
            const float* src = hb + (tb * 16 + r) * HID + kk * 32 + g * 8;
            float4 x0 = *(const float4*)src;
            float4 x1 = *(const float4*)(src + 4);
            Ah[tb][kk] = mk8(pk2(x0.x, x0.y), pk2(x0.z, x0.w),
                             pk2(x1.x, x1.y), pk2(x1.z, x1.w));
        }

    floatx4 E[3][3];
    #pragma unroll
    for (int tb = 0; tb < 3; ++tb)
        #pragma unroll
        for (int nb = 0; nb < 3; ++nb) E[tb][nb] = (floatx4)0.f;

    #pragma unroll
    for (int kk = 0; kk < 2; ++kk) {
        floatx4 Gacc[2][3];
        #pragma unroll
        for (int t = 0; t < 2; ++t)
            #pragma unroll
            for (int nb = 0; nb < 3; ++nb) Gacc[t][nb] = (floatx4)0.f;
        #pragma unroll
        for (int tbL = 0; tbL < 2; ++tbL) {
            const int tbG = kk * 2 + tbL;
            #pragma unroll
            for (int ak = 0; ak < 2; ++ak) {
                half8 Mhi = *(const half8*)(ws + WS_M +
                    (size_t)((((e * 2 + 0) * 4 + tbG) * 2 + ak) * 64 + lane) * 8);
                #pragma unroll
                for (int nb = 0; nb < 3; ++nb)
                    Gacc[tbL][nb] = __builtin_amdgcn_mfma_f32_16x16x32_f16(Mhi, Ah[nb][ak], Gacc[tbL][nb], 0, 0, 0);
            }
        }
        #pragma unroll
        for (int nb = 0; nb < 3; ++nb) {
            uint p0[2], p1[2];
            #pragma unroll
            for (int d = 0; d < 2; ++d) {
                p0[d] = pk2(Gacc[0][nb][2 * d], Gacc[0][nb][2 * d + 1]);
                p1[d] = pk2(Gacc[1][nb][2 * d], Gacc[1][nb][2 * d + 1]);
            }
            half8 Bh = regroup2(p0, p1, laneA, hiT);
            #pragma unroll
            for (int tb = 0; tb < 3; ++tb)
                E[tb][nb] = __builtin_amdgcn_mfma_f32_16x16x32_f16(Ah[tb][kk], Bh, E[tb][nb], 0, 0, 0);
        }
    }

    #pragma unroll
    for (int nb = 0; nb < 3; ++nb) {
        float m = E[0][nb][0];
        #pragma unroll
        for (int tb = 0; tb < 3; ++tb)
            #pragma unroll
            for (int rr = 0; rr < 4; ++rr) m = fmaxf(m, E[tb][nb][rr]);
        m = fmaxf(m, __shfl_xor(m, 16));
        m = fmaxf(m, __shfl_xor(m, 32));
        #pragma unroll
        for (int tb = 0; tb < 3; ++tb)
            #pragma unroll
            for (int rr = 0; rr < 4; ++rr) E[tb][nb][rr] = __expf(E[tb][nb][rr] - m);
    }

    half8 PF[3][2];
    #pragma unroll
    for (int tbT = 0; tbT < 3; ++tbT) {
        uint pk[3][2];
        #pragma unroll
        for (int t = 0; t < 3; ++t)
            #pragma unroll
            for (int d = 0; d < 2; ++d)
                pk[t][d] = pk2(E[t][tbT][2 * d], E[t][tbT][2 * d + 1]);
        PF[tbT][0] = regroup2(pk[0], pk[1], laneA, hiT);
        PF[tbT][1] = regroup1pad(pk[2], laneA, hiT);
    }

    half8 vb[2][2];
    {
        half8 WV[2][2];
        #pragma unroll
        for (int kk = 0; kk < 2; ++kk)
            #pragma unroll
            for (int nb = 0; nb < 2; ++nb)
                WV[kk][nb] = *(const half8*)(ws + WS_WV + e * 2048 + (size_t)((kk * 2 + nb) * 64 + lane) * 8);
        floatx4 vacc[3][2];
        #pragma unroll
        for (int tb = 0; tb < 3; ++tb) { vacc[tb][0] = (floatx4)0.f; vacc[tb][1] = (floatx4)0.f; }
        #pragma unroll
        for (int kk = 0; kk < 2; ++kk)
            #pragma unroll
            for (int tb = 0; tb < 3; ++tb)
                #pragma unroll
                for (int nb = 0; nb < 2; ++nb)
                    vacc[tb][nb] = __builtin_amdgcn_mfma_f32_16x16x32_f16(Ah[tb][kk], WV[kk][nb], vacc[tb][nb], 0, 0, 0);
        #pragma unroll
        for (int nb = 0; nb < 2; ++nb) {
            uint pkv[3][2];
            #pragma unroll
            for (int tb = 0; tb < 3; ++tb)
                #pragma unroll
                for (int d = 0; d < 2; ++d)
                    pkv[tb][d] = pk2(vacc[tb][nb][2 * d], vacc[tb][nb][2 * d + 1]);
            vb[nb][0] = regroup2(pkv[0], pkv[1], laneA, hiT);
            vb[nb][1] = regroup1pad(pkv[2], laneA, hiT);
        }
    }

    floatx4 att[3][2];
    #pragma unroll
    for (int tb = 0; tb < 3; ++tb) { att[tb][0] = (floatx4)0.f; att[tb][1] = (floatx4)0.f; }
    #pragma unroll
    for (int kk = 0; kk < 2; ++kk)
        #pragma unroll
        for (int tb = 0; tb < 3; ++tb) {
            att[tb][0] = __builtin_amdgcn_mfma_f32_16x16x32_f16(PF[tb][kk], vb[0][kk], att[tb][0], 0, 0, 0);
            att[tb][1] = __builtin_amdgcn_mfma_f32_16x16x32_f16(PF[tb][kk], vb[1][kk], att[tb][1], 0, 0, 0);
        }

    // ===== cosine: mems/nm from LDS, (nu,nr) packed f16, DPP reduce =========
    #pragma unroll
    for (int tb = 0; tb < 3; ++tb) {
        uint4t mp = *(const uint4t*)&s_mem_pk[(tb * 64 + lane) * 4];
        #pragma unroll
        for (int rr = 0; rr < 4; ++rr) {
            int t = 16 * tb + 4 * g + rr;
            float a0 = att[tb][0][rr], a1 = att[tb][1][rr];
            float m0 = (rr & 1) ? f16hi(mp[rr >> 1]) : f16lo(mp[rr >> 1]);
            float m1 = (rr & 1) ? f16hi(mp[2 + (rr >> 1)]) : f16lo(mp[2 + (rr >> 1)]);
            float nu = a0 * m0 + a1 * m1;
            float nr = a0 * a0 + a1 * a1;
            uint nur = dpp_reduce_pk(pk2(nu * 0.015625f, nr * 0.015625f));
            if (r == 0) {
                float nuv = f16lo(nur), nrv = f16hi(nur);
                float den = fmaxf(8.f * sqrtf(nrv * s_nm[t]), 1e-8f);
                out[(bn * TT + t) * 3 + e] = 64.f * nuv / den;
            }
        }
    }
}

extern "C" void kernel_launch(void* const* d_in, const int* in_sizes, int n_in,
                              void* d_out, int out_size, void* d_ws, size_t ws_size,
                              hipStream_t stream) {
    const float* input       = (const float*)d_in[0];
    const float* h0          = (const float*)d_in[1];
    const float* h1          = (const float*)d_in[2];
    const float* h2          = (const float*)d_in[3];
    const float* memory      = (const float*)d_in[4];
    const float* input_query = (const float*)d_in[5];
    const float* hid_query   = (const float*)d_in[6];
    const float* key_w       = (const float*)d_in[7];
    const float* value_w     = (const float*)d_in[8];
    float* out = (float*)d_out;
    _Float16* ws = (_Float16*)d_ws;   // 65536 bytes used

    hipLaunchKernelGGL(prep_frags, dim3(3), dim3(256), 0, stream,
                       hid_query, key_w, value_w, memory, ws);
    hipLaunchKernelGGL(testam_wave, dim3(16 * 1024), dim3(192), 0, stream,
                       input, h0, h1, h2, input_query, ws, out);
}

// Round 14
// 193.535 us; speedup vs baseline: 1.2854x; 1.0051x over previous
//
#include <hip/hip_runtime.h>

typedef _Float16 half8 __attribute__((ext_vector_type(8)));
typedef __fp16 fp16x2 __attribute__((ext_vector_type(2)));
typedef float floatx4 __attribute__((ext_vector_type(4)));
typedef unsigned int uint;
typedef uint uint4t __attribute__((ext_vector_type(4)));

#if __has_builtin(__builtin_amdgcn_permlane16_swap) && __has_builtin(__builtin_amdgcn_permlane32_swap)
#define HAVE_PERMLANE 1
#else
#define HAVE_PERMLANE 0
#endif

namespace {
constexpr int TT = 48, HID = 64, MH = 32, MS = 20;
// d_ws offsets in half elements (total 32768 halves = 64 KiB)
constexpr int WS_WV   = 0;        // value_w B-frags: [e][kk][nb] * 512
constexpr int WS_MEMA = 6144;     // mem A-frags (rows s, zero s>=20): 1024
constexpr int WS_MEMB = 7168;     // mem B-frags (k=s, col m, zero s>=20): 1024
constexpr int WS_M    = 8192;     // M^T A-frags: [e][hl][tbG][ak] * 512 (hl=1 unused)
}

static __device__ inline uint pk2(float a, float b) {
    fp16x2 h = __builtin_amdgcn_cvt_pkrtz(a, b);
    return __builtin_bit_cast(uint, h);
}
static __device__ inline half8 mk8(uint a, uint b, uint c, uint d) {
    uint4t u = {a, b, c, d};
    return __builtin_bit_cast(half8, u);
}
static __device__ inline uint pkadd(uint a, uint b) {
    fp16x2 x = __builtin_bit_cast(fp16x2, a);
    fp16x2 y = __builtin_bit_cast(fp16x2, b);
    fp16x2 z = x + y;                      // v_pk_add_f16
    return __builtin_bit_cast(uint, z);
}
static __device__ inline float f16lo(uint u) {
    fp16x2 f = __builtin_bit_cast(fp16x2, u); return (float)f[0];
}
static __device__ inline float f16hi(uint u) {
    fp16x2 f = __builtin_bit_cast(fp16x2, u); return (float)f[1];
}
// DPP lane-permute (within 16-lane rows)
template<int CTRL>
static __device__ inline uint dpp_mov(uint x) {
    return (uint)__builtin_amdgcn_update_dpp(0, (int)x, CTRL, 0xF, 0xF, true);
}
static __device__ inline uint dpp_reduce_pk(uint v) {
    v = pkadd(v, dpp_mov<0x128>(v));   // +ror8
    v = pkadd(v, dpp_mov<0x124>(v));   // +ror4
    v = pkadd(v, dpp_mov<0x4E>(v));    // +xor2
    v = pkadd(v, dpp_mov<0xB1>(v));    // +xor1
    return v;
}
static __device__ inline float dpp_reduce_f32(float v) {
    #define STEP(C) { int t = __builtin_amdgcn_update_dpp(0, __builtin_bit_cast(int, v), C, 0xF, 0xF, true); \
                      v += __builtin_bit_cast(float, t); }
    STEP(0x128) STEP(0x124) STEP(0x4E) STEP(0xB1)
    #undef STEP
    return v;
}

#if HAVE_PERMLANE
// compiler-modeled dual-output swaps (builtin returns {new_vdst, new_src})
static __device__ inline void pl32swap(uint& a, uint& b) {
    auto r = __builtin_amdgcn_permlane32_swap(a, b, false, false);
    a = (uint)r[0]; b = (uint)r[1];
}
static __device__ inline void pl16swap(uint& a, uint& b) {
    auto r = __builtin_amdgcn_permlane16_swap(a, b, false, false);
    a = (uint)r[0]; b = (uint)r[1];
}
#endif

// C-layout -> fragment regroup. Target permutation (verified rounds 6-12):
// w[d][g,r] = p_{g>=2}[(g&1)*32+r], w[2+d][g,r] = p_{g>=2}[(g&1)*32+16+r]
static __device__ inline half8 regroup2(const uint p0[2], const uint p1[2],
                                        int laneA, bool hiT) {
#if HAVE_PERMLANE
    uint w0 = p0[0], w2 = p1[0];
    pl32swap(w0, w2); pl16swap(w0, w2);
    uint w1 = p0[1], w3 = p1[1];
    pl32swap(w1, w3); pl16swap(w1, w3);
    return mk8(w0, w1, w2, w3);
#else
    uint w[4];
    #pragma unroll
    for (int d = 0; d < 2; ++d) {
        int a0 = __shfl((int)p0[d], laneA);
        int a1 = __shfl((int)p1[d], laneA);
        int b0 = __shfl((int)p0[d], laneA + 16);
        int b1 = __shfl((int)p1[d], laneA + 16);
        w[d]     = hiT ? (uint)a1 : (uint)a0;
        w[2 + d] = hiT ? (uint)b1 : (uint)b0;
    }
    return mk8(w[0], w[1], w[2], w[3]);
#endif
}
static __device__ inline half8 regroup1pad(const uint p2[2], int laneA, bool hiT) {
#if HAVE_PERMLANE
    uint w0 = p2[0], w2 = 0u;
    pl32swap(w0, w2); pl16swap(w0, w2);
    uint w1 = p2[1], w3 = 0u;
    pl32swap(w1, w3); pl16swap(w1, w3);
    return mk8(w0, w1, w2, w3);
#else
    uint w[4];
    #pragma unroll
    for (int d = 0; d < 2; ++d) {
        int a2 = __shfl((int)p2[d], laneA);
        int b2 = __shfl((int)p2[d], laneA + 16);
        w[d]     = hiT ? 0u : (uint)a2;
        w[2 + d] = hiT ? 0u : (uint)b2;
    }
    return mk8(w[0], w[1], w[2], w[3]);
#endif
}
// max across lane-groups {r}, {16+r}, {32+r}, {48+r} -> all lanes
// (copy+swap+fmax is correct under EITHER swap direction)
static __device__ inline float wavemax_1632(float m) {
#if HAVE_PERMLANE
    uint a = __builtin_bit_cast(uint, m), b = a;
    pl16swap(a, b);
    float x = fmaxf(__builtin_bit_cast(float, a), __builtin_bit_cast(float, b));
    a = __builtin_bit_cast(uint, x); b = a;
    pl32swap(a, b);
    return fmaxf(__builtin_bit_cast(float, a), __builtin_bit_cast(float, b));
#else
    m = fmaxf(m, __shfl_xor(m, 16));
    m = fmaxf(m, __shfl_xor(m, 32));
    return m;
#endif
}

// Prep: per-expert M = Wq*Wk^T (fp32) -> M^T A-frags; value_w B-frags; mem frags.
__global__ __launch_bounds__(256)
void prep_frags(const float* __restrict__ hid_query,
                const float* __restrict__ key_w,
                const float* __restrict__ value_w,
                const float* __restrict__ memory,
                _Float16* __restrict__ ws)
{
    const int e = blockIdx.x, tid = threadIdx.x;
    __shared__ float sWq[HID * MH], sWk[HID * MH], sM[HID * HID];
    for (int i = tid; i < HID * MH; i += 256) {
        sWq[i] = hid_query[e * HID * MH + i];
        sWk[i] = key_w[e * HID * MH + i];
    }
    __syncthreads();
    for (int i = tid; i < HID * HID; i += 256) {
        int a = i >> 6, b = i & 63;
        float acc = 0.f;
        #pragma unroll
        for (int m = 0; m < MH; ++m) acc = fmaf(sWq[a * MH + m], sWk[b * MH + m], acc);
        sM[i] = acc;
    }
    __syncthreads();
    for (int i = tid; i < 16 * 512; i += 256) {
        int j = i & 7, lane = (i >> 3) & 63, ak = (i >> 9) & 1, tbG = (i >> 10) & 3, hl = (i >> 12) & 1;
        float v = sM[(32 * ak + 8 * (lane >> 4) + j) * 64 + 16 * tbG + (lane & 15)];
        _Float16 hi = (_Float16)v;
        ws[WS_M + (size_t)((((e * 2 + hl) * 4 + tbG) * 2 + ak) << 9) + (i & 511)] =
            hl ? (_Float16)(v - (float)hi) : hi;
    }
    for (int i = tid; i < 2048; i += 256) {
        int j = i & 7, lane = (i >> 3) & 63, nb = (i >> 9) & 1, kk = (i >> 10) & 1;
        int h = kk * 32 + (lane >> 4) * 8 + j;
        int m = nb * 16 + (lane & 15);
        ws[WS_WV + e * 2048 + (i & 2047)] = (_Float16)value_w[((size_t)e * HID + h) * MH + m];
    }
    if (e == 0) {
        for (int i = tid; i < 1024; i += 256) {
            int j = i & 7, lane = (i >> 3) & 63, sb = i >> 9;
            int s = 16 * sb + (lane & 15);
            int m = (lane >> 4) * 8 + j;
            ws[WS_MEMA + i] = (s < MS) ? (_Float16)memory[s * MH + m] : (_Float16)0.f;
        }
        for (int i = tid; i < 1024; i += 256) {
            int j = i & 7, lane = (i >> 3) & 63, nb = i >> 9;
            int s = (lane >> 4) * 8 + j;
            int m = 16 * nb + (lane & 15);
            ws[WS_MEMB + i] = (s < MS) ? (_Float16)memory[s * MH + m] : (_Float16)0.f;
        }
    }
}

// Block = one bn, 3 waves = 3 experts. Phase A split by tb across the 3 waves,
// broadcast via 3.5 KB LDS, one barrier.
__global__ __launch_bounds__(192, 4)
void testam_wave(const float* __restrict__ input,
                 const float* __restrict__ h0,
                 const float* __restrict__ h1,
                 const float* __restrict__ h2,
                 const float* __restrict__ input_query,
                 const _Float16* __restrict__ ws,
                 float* __restrict__ out)
{
    __shared__ __align__(16) uint s_mem_pk[3 * 64 * 4];   // [tb][lane][4 dwords]
    __shared__ float s_nm[TT];

    const int tid  = threadIdx.x;
    const int e    = tid >> 6;          // wave id = expert
    const int lane = tid & 63;
    const int r = lane & 15, g = lane >> 4;
    const size_t bn = blockIdx.x;

    const int laneA = (g & 1) * 32 + r;   // used only by the shfl fallback
    const bool hiT = (g >= 2);

    // ===== phase A, 1/3 per wave (tb = e): memories + norms -> LDS ==========
    {
        const int tb = e;
        half8 memA0 = *(const half8*)(ws + WS_MEMA + (size_t)lane * 8);
        half8 memA1 = *(const half8*)(ws + WS_MEMA + (size_t)(64 + lane) * 8);
        half8 memB0 = *(const half8*)(ws + WS_MEMB + (size_t)lane * 8);
        half8 memB1 = *(const half8*)(ws + WS_MEMB + (size_t)(64 + lane) * 8);

        float4 iqa = *(const float4*)(input_query + g * 8);
        float4 iqb = *(const float4*)(input_query + g * 8 + 4);
        float4 iqc = *(const float4*)(input_query + 32 + g * 8);
        float4 iqd = *(const float4*)(input_query + 32 + g * 8 + 4);
        float iq0[8] = {iqa.x, iqa.y, iqa.z, iqa.w, iqb.x, iqb.y, iqb.z, iqb.w};
        float iq1[8] = {iqc.x, iqc.y, iqc.z, iqc.w, iqd.x, iqd.y, iqd.z, iqd.w};

        const float2 in2 = *(const float2*)(input + bn * 96 + (16 * tb + r) * 2);
        float f[8];
        #pragma unroll
        for (int j = 0; j < 8; ++j) f[j] = in2.x * iq0[j] + in2.y * iq1[j];
        half8 qb = mk8(pk2(f[0], f[1]), pk2(f[2], f[3]), pk2(f[4], f[5]), pk2(f[6], f[7]));
        floatx4 Em0 = __builtin_amdgcn_mfma_f32_16x16x32_f16(memA0, qb, (floatx4)0.f, 0, 0, 0);
        floatx4 Em1 = __builtin_amdgcn_mfma_f32_16x16x32_f16(memA1, qb, (floatx4)0.f, 0, 0, 0);

        float mx = Em0[0];
        #pragma unroll
        for (int rr = 1; rr < 4; ++rr) mx = fmaxf(mx, Em0[rr]);
        #pragma unroll
        for (int rr = 0; rr < 4; ++rr) mx = fmaxf(mx, Em1[rr]);
        mx = wavemax_1632(mx);
        uint pA0[2], pA1[2];
        #pragma unroll
        for (int d = 0; d < 2; ++d) {
            pA0[d] = pk2(__expf(Em0[2 * d] - mx), __expf(Em0[2 * d + 1] - mx));
            pA1[d] = pk2(__expf(Em1[2 * d] - mx), __expf(Em1[2 * d + 1] - mx));
        }
        half8 pA = regroup2(pA0, pA1, laneA, hiT);
        floatx4 m0 = __builtin_amdgcn_mfma_f32_16x16x32_f16(pA, memB0, (floatx4)0.f, 0, 0, 0);
        floatx4 m1 = __builtin_amdgcn_mfma_f32_16x16x32_f16(pA, memB1, (floatx4)0.f, 0, 0, 0);
        #pragma unroll
        for (int rr = 0; rr < 4; ++rr) {
            float nm = dpp_reduce_f32(m0[rr] * m0[rr] + m1[rr] * m1[rr]);
            if (r == 0) s_nm[16 * tb + 4 * g + rr] = nm;
        }
        uint4t mp = { pk2(m0[0], m0[1]), pk2(m0[2], m0[3]),
                      pk2(m1[0], m1[1]), pk2(m1[2], m1[3]) };
        *(uint4t*)&s_mem_pk[(tb * 64 + lane) * 4] = mp;
    }
    __syncthreads();

    // ===== expert body ======================================================
    const float* hp = (e == 0) ? h0 : (e == 1 ? h1 : h2);
    const float* hb = hp + bn * (size_t)(TT * HID);

    half8 Ah[3][2];
    #pragma unroll
    for (int tb = 0; tb < 3; ++tb)
        #pragma unroll
        for (int kk = 0; kk < 2; ++kk) {
            const float* src = hb + (tb * 16 + r) * HID + kk * 32 + g * 8;
            float4 x0 = *(const float4*)src;
            float4 x1 = *(const float4*)(src + 4);
            Ah[tb][kk] = mk8(pk2(x0.x, x0.y), pk2(x0.z, x0.w),
                             pk2(x1.x, x1.y), pk2(x1.z, x1.w));
        }

    floatx4 E[3][3];
    #pragma unroll
    for (int tb = 0; tb < 3; ++tb)
        #pragma unroll
        for (int nb = 0; nb < 3; ++nb) E[tb][nb] = (floatx4)0.f;

    #pragma unroll
    for (int kk = 0; kk < 2; ++kk) {
        floatx4 Gacc[2][3];
        #pragma unroll
        for (int t = 0; t < 2; ++t)
            #pragma unroll
            for (int nb = 0; nb < 3; ++nb) Gacc[t][nb] = (floatx4)0.f;
        #pragma unroll
        for (int tbL = 0; tbL < 2; ++tbL) {
            const int tbG = kk * 2 + tbL;
            #pragma unroll
            for (int ak = 0; ak < 2; ++ak) {
                half8 Mhi = *(const half8*)(ws + WS_M +
                    (size_t)((((e * 2 + 0) * 4 + tbG) * 2 + ak) * 64 + lane) * 8);
                #pragma unroll
                for (int nb = 0; nb < 3; ++nb)
                    Gacc[tbL][nb] = __builtin_amdgcn_mfma_f32_16x16x32_f16(Mhi, Ah[nb][ak], Gacc[tbL][nb], 0, 0, 0);
            }
        }
        #pragma unroll
        for (int nb = 0; nb < 3; ++nb) {
            uint p0[2], p1[2];
            #pragma unroll
            for (int d = 0; d < 2; ++d) {
                p0[d] = pk2(Gacc[0][nb][2 * d], Gacc[0][nb][2 * d + 1]);
                p1[d] = pk2(Gacc[1][nb][2 * d], Gacc[1][nb][2 * d + 1]);
            }
            half8 Bh = regroup2(p0, p1, laneA, hiT);
            #pragma unroll
            for (int tb = 0; tb < 3; ++tb)
                E[tb][nb] = __builtin_amdgcn_mfma_f32_16x16x32_f16(Ah[tb][kk], Bh, E[tb][nb], 0, 0, 0);
        }
    }

    #pragma unroll
    for (int nb = 0; nb < 3; ++nb) {
        float m = E[0][nb][0];
        #pragma unroll
        for (int tb = 0; tb < 3; ++tb)
            #pragma unroll
            for (int rr = 0; rr < 4; ++rr) m = fmaxf(m, E[tb][nb][rr]);
        m = wavemax_1632(m);
        #pragma unroll
        for (int tb = 0; tb < 3; ++tb)
            #pragma unroll
            for (int rr = 0; rr < 4; ++rr) E[tb][nb][rr] = __expf(E[tb][nb][rr] - m);
    }

    half8 PF[3][2];
    #pragma unroll
    for (int tbT = 0; tbT < 3; ++tbT) {
        uint pk[3][2];
        #pragma unroll
        for (int t = 0; t < 3; ++t)
            #pragma unroll
            for (int d = 0; d < 2; ++d)
                pk[t][d] = pk2(E[t][tbT][2 * d], E[t][tbT][2 * d + 1]);
        PF[tbT][0] = regroup2(pk[0], pk[1], laneA, hiT);
        PF[tbT][1] = regroup1pad(pk[2], laneA, hiT);
    }

    half8 vb[2][2];
    {
        half8 WV[2][2];
        #pragma unroll
        for (int kk = 0; kk < 2; ++kk)
            #pragma unroll
            for (int nb = 0; nb < 2; ++nb)
                WV[kk][nb] = *(const half8*)(ws + WS_WV + e * 2048 + (size_t)((kk * 2 + nb) * 64 + lane) * 8);
        floatx4 vacc[3][2];
        #pragma unroll
        for (int tb = 0; tb < 3; ++tb) { vacc[tb][0] = (floatx4)0.f; vacc[tb][1] = (floatx4)0.f; }
        #pragma unroll
        for (int kk = 0; kk < 2; ++kk)
            #pragma unroll
            for (int tb = 0; tb < 3; ++tb)
                #pragma unroll
                for (int nb = 0; nb < 2; ++nb)
                    vacc[tb][nb] = __builtin_amdgcn_mfma_f32_16x16x32_f16(Ah[tb][kk], WV[kk][nb], vacc[tb][nb], 0, 0, 0);
        #pragma unroll
        for (int nb = 0; nb < 2; ++nb) {
            uint pkv[3][2];
            #pragma unroll
            for (int tb = 0; tb < 3; ++tb)
                #pragma unroll
                for (int d = 0; d < 2; ++d)
                    pkv[tb][d] = pk2(vacc[tb][nb][2 * d], vacc[tb][nb][2 * d + 1]);
            vb[nb][0] = regroup2(pkv[0], pkv[1], laneA, hiT);
            vb[nb][1] = regroup1pad(pkv[2], laneA, hiT);
        }
    }

    floatx4 att[3][2];
    #pragma unroll
    for (int tb = 0; tb < 3; ++tb) { att[tb][0] = (floatx4)0.f; att[tb][1] = (floatx4)0.f; }
    #pragma unroll
    for (int kk = 0; kk < 2; ++kk)
        #pragma unroll
        for (int tb = 0; tb < 3; ++tb) {
            att[tb][0] = __builtin_amdgcn_mfma_f32_16x16x32_f16(PF[tb][kk], vb[0][kk], att[tb][0], 0, 0, 0);
            att[tb][1] = __builtin_amdgcn_mfma_f32_16x16x32_f16(PF[tb][kk], vb[1][kk], att[tb][1], 0, 0, 0);
        }

    // ===== cosine: mems/nm from LDS, (nu,nr) packed f16, DPP reduce =========
    #pragma unroll
    for (int tb = 0; tb < 3; ++tb) {
        uint4t mp = *(const uint4t*)&s_mem_pk[(tb * 64 + lane) * 4];
        #pragma unroll
        for (int rr = 0; rr < 4; ++rr) {
            int t = 16 * tb + 4 * g + rr;
            float a0 = att[tb][0][rr], a1 = att[tb][1][rr];
            float m0 = (rr & 1) ? f16hi(mp[rr >> 1]) : f16lo(mp[rr >> 1]);
            float m1 = (rr & 1) ? f16hi(mp[2 + (rr >> 1)]) : f16lo(mp[2 + (rr >> 1)]);
            float nu = a0 * m0 + a1 * m1;
            float nr = a0 * a0 + a1 * a1;
            uint nur = dpp_reduce_pk(pk2(nu * 0.015625f, nr * 0.015625f));
            if (r == 0) {
                float nuv = f16lo(nur), nrv = f16hi(nur);
                float den = fmaxf(8.f * sqrtf(nrv * s_nm[t]), 1e-8f);
                out[(bn * TT + t) * 3 + e] = 64.f * nuv / den;
            }
        }
    }
}

extern "C" void kernel_launch(void* const* d_in, const int* in_sizes, int n_in,
                              void* d_out, int out_size, void* d_ws, size_t ws_size,
                              hipStream_t stream) {
    const float* input       = (const float*)d_in[0];
    const float* h0          = (const float*)d_in[1];
    const float* h1          = (const float*)d_in[2];
    const float* h2          = (const float*)d_in[3];
    const float* memory      = (const float*)d_in[4];
    const float* input_query = (const float*)d_in[5];
    const float* hid_query   = (const float*)d_in[6];
    const float* key_w       = (const float*)d_in[7];
    const float* value_w     = (const float*)d_in[8];
    float* out = (float*)d_out;
    _Float16* ws = (_Float16*)d_ws;   // 65536 bytes used

    hipLaunchKernelGGL(prep_frags, dim3(3), dim3(256), 0, stream,
                       hid_query, key_w, value_w, memory, ws);
    hipLaunchKernelGGL(testam_wave, dim3(16 * 1024), dim3(192), 0, stream,
                       input, h0, h1, h2, input_query, ws, out);
}

// Round 15
// 178.895 us; speedup vs baseline: 1.3906x; 1.0818x over previous
//
#include <hip/hip_runtime.h>

typedef _Float16 half8 __attribute__((ext_vector_type(8)));
typedef __fp16 fp16x2 __attribute__((ext_vector_type(2)));
typedef float floatx4 __attribute__((ext_vector_type(4)));
typedef unsigned int uint;
typedef uint uint4t __attribute__((ext_vector_type(4)));

#if __has_builtin(__builtin_amdgcn_permlane16_swap) && __has_builtin(__builtin_amdgcn_permlane32_swap)
#define HAVE_PERMLANE 1
#else
#define HAVE_PERMLANE 0
#endif

namespace {
constexpr int TT = 48, HID = 64, MH = 32, MS = 20;
// d_ws offsets in half elements (total 32768 halves = 64 KiB)
constexpr int WS_WV   = 0;        // value_w B-frags: [e][kk][nb] * 512
constexpr int WS_MEMA = 6144;     // mem A-frags (rows s, zero s>=20): 1024
constexpr int WS_MEMB = 7168;     // mem B-frags (k=s, col m, zero s>=20): 1024
constexpr int WS_M    = 8192;     // M^T A-frags: [e][hl][tbG][ak] * 512 (hl=1 unused)
}

static __device__ inline uint pk2(float a, float b) {
    fp16x2 h = __builtin_amdgcn_cvt_pkrtz(a, b);
    return __builtin_bit_cast(uint, h);
}
static __device__ inline half8 mk8(uint a, uint b, uint c, uint d) {
    uint4t u = {a, b, c, d};
    return __builtin_bit_cast(half8, u);
}
static __device__ inline uint pkadd(uint a, uint b) {
    fp16x2 x = __builtin_bit_cast(fp16x2, a);
    fp16x2 y = __builtin_bit_cast(fp16x2, b);
    fp16x2 z = x + y;                      // v_pk_add_f16
    return __builtin_bit_cast(uint, z);
}
static __device__ inline float f16lo(uint u) {
    fp16x2 f = __builtin_bit_cast(fp16x2, u); return (float)f[0];
}
static __device__ inline float f16hi(uint u) {
    fp16x2 f = __builtin_bit_cast(fp16x2, u); return (float)f[1];
}
// DPP lane-permute (within 16-lane rows)
template<int CTRL>
static __device__ inline uint dpp_mov(uint x) {
    return (uint)__builtin_amdgcn_update_dpp(0, (int)x, CTRL, 0xF, 0xF, true);
}
static __device__ inline uint dpp_reduce_pk(uint v) {
    v = pkadd(v, dpp_mov<0x128>(v));   // +ror8
    v = pkadd(v, dpp_mov<0x124>(v));   // +ror4
    v = pkadd(v, dpp_mov<0x4E>(v));    // +xor2
    v = pkadd(v, dpp_mov<0xB1>(v));    // +xor1
    return v;
}
static __device__ inline float dpp_reduce_f32(float v) {
    #define STEP(C) { int t = __builtin_amdgcn_update_dpp(0, __builtin_bit_cast(int, v), C, 0xF, 0xF, true); \
                      v += __builtin_bit_cast(float, t); }
    STEP(0x128) STEP(0x124) STEP(0x4E) STEP(0xB1)
    #undef STEP
    return v;
}

#if HAVE_PERMLANE
// compiler-modeled dual-output swaps (builtin returns {new_vdst, new_src})
static __device__ inline void pl32swap(uint& a, uint& b) {
    auto r = __builtin_amdgcn_permlane32_swap(a, b, false, false);
    a = (uint)r[0]; b = (uint)r[1];
}
static __device__ inline void pl16swap(uint& a, uint& b) {
    auto r = __builtin_amdgcn_permlane16_swap(a, b, false, false);
    a = (uint)r[0]; b = (uint)r[1];
}
#endif

// C-layout -> fragment regroup. Target permutation (verified rounds 6-12):
// w[d][g,r] = p_{g>=2}[(g&1)*32+r], w[2+d][g,r] = p_{g>=2}[(g&1)*32+16+r]
static __device__ inline half8 regroup2(const uint p0[2], const uint p1[2],
                                        int laneA, bool hiT) {
#if HAVE_PERMLANE
    uint w0 = p0[0], w2 = p1[0];
    pl32swap(w0, w2); pl16swap(w0, w2);
    uint w1 = p0[1], w3 = p1[1];
    pl32swap(w1, w3); pl16swap(w1, w3);
    return mk8(w0, w1, w2, w3);
#else
    uint w[4];
    #pragma unroll
    for (int d = 0; d < 2; ++d) {
        int a0 = __shfl((int)p0[d], laneA);
        int a1 = __shfl((int)p1[d], laneA);
        int b0 = __shfl((int)p0[d], laneA + 16);
        int b1 = __shfl((int)p1[d], laneA + 16);
        w[d]     = hiT ? (uint)a1 : (uint)a0;
        w[2 + d] = hiT ? (uint)b1 : (uint)b0;
    }
    return mk8(w[0], w[1], w[2], w[3]);
#endif
}
static __device__ inline half8 regroup1pad(const uint p2[2], int laneA, bool hiT) {
#if HAVE_PERMLANE
    uint w0 = p2[0], w2 = 0u;
    pl32swap(w0, w2); pl16swap(w0, w2);
    uint w1 = p2[1], w3 = 0u;
    pl32swap(w1, w3); pl16swap(w1, w3);
    return mk8(w0, w1, w2, w3);
#else
    uint w[4];
    #pragma unroll
    for (int d = 0; d < 2; ++d) {
        int a2 = __shfl((int)p2[d], laneA);
        int b2 = __shfl((int)p2[d], laneA + 16);
        w[d]     = hiT ? 0u : (uint)a2;
        w[2 + d] = hiT ? 0u : (uint)b2;
    }
    return mk8(w[0], w[1], w[2], w[3]);
#endif
}
// max across lane-groups {r}, {16+r}, {32+r}, {48+r} -> all lanes
static __device__ inline float wavemax_1632(float m) {
#if HAVE_PERMLANE
    uint a = __builtin_bit_cast(uint, m), b = a;
    pl16swap(a, b);
    float x = fmaxf(__builtin_bit_cast(float, a), __builtin_bit_cast(float, b));
    a = __builtin_bit_cast(uint, x); b = a;
    pl32swap(a, b);
    return fmaxf(__builtin_bit_cast(float, a), __builtin_bit_cast(float, b));
#else
    m = fmaxf(m, __shfl_xor(m, 16));
    m = fmaxf(m, __shfl_xor(m, 32));
    return m;
#endif
}

// Prep: per-expert M = Wq*Wk^T (fp32) -> M^T A-frags; value_w B-frags; mem frags.
__global__ __launch_bounds__(256)
void prep_frags(const float* __restrict__ hid_query,
                const float* __restrict__ key_w,
                const float* __restrict__ value_w,
                const float* __restrict__ memory,
                _Float16* __restrict__ ws)
{
    const int e = blockIdx.x, tid = threadIdx.x;
    __shared__ float sWq[HID * MH], sWk[HID * MH], sM[HID * HID];
    for (int i = tid; i < HID * MH; i += 256) {
        sWq[i] = hid_query[e * HID * MH + i];
        sWk[i] = key_w[e * HID * MH + i];
    }
    __syncthreads();
    for (int i = tid; i < HID * HID; i += 256) {
        int a = i >> 6, b = i & 63;
        float acc = 0.f;
        #pragma unroll
        for (int m = 0; m < MH; ++m) acc = fmaf(sWq[a * MH + m], sWk[b * MH + m], acc);
        sM[i] = acc;
    }
    __syncthreads();
    for (int i = tid; i < 16 * 512; i += 256) {
        int j = i & 7, lane = (i >> 3) & 63, ak = (i >> 9) & 1, tbG = (i >> 10) & 3, hl = (i >> 12) & 1;
        float v = sM[(32 * ak + 8 * (lane >> 4) + j) * 64 + 16 * tbG + (lane & 15)];
        _Float16 hi = (_Float16)v;
        ws[WS_M + (size_t)((((e * 2 + hl) * 4 + tbG) * 2 + ak) << 9) + (i & 511)] =
            hl ? (_Float16)(v - (float)hi) : hi;
    }
    for (int i = tid; i < 2048; i += 256) {
        int j = i & 7, lane = (i >> 3) & 63, nb = (i >> 9) & 1, kk = (i >> 10) & 1;
        int h = kk * 32 + (lane >> 4) * 8 + j;
        int m = nb * 16 + (lane & 15);
        ws[WS_WV + e * 2048 + (i & 2047)] = (_Float16)value_w[((size_t)e * HID + h) * MH + m];
    }
    if (e == 0) {
        for (int i = tid; i < 1024; i += 256) {
            int j = i & 7, lane = (i >> 3) & 63, sb = i >> 9;
            int s = 16 * sb + (lane & 15);
            int m = (lane >> 4) * 8 + j;
            ws[WS_MEMA + i] = (s < MS) ? (_Float16)memory[s * MH + m] : (_Float16)0.f;
        }
        for (int i = tid; i < 1024; i += 256) {
            int j = i & 7, lane = (i >> 3) & 63, nb = i >> 9;
            int s = (lane >> 4) * 8 + j;
            int m = 16 * nb + (lane & 15);
            ws[WS_MEMB + i] = (s < MS) ? (_Float16)memory[s * MH + m] : (_Float16)0.f;
        }
    }
}

// Block = one bn, 3 waves = 3 experts. Phase A split by tb across the 3 waves,
// broadcast via 3.5 KB LDS, one barrier. h/WV loads issued BEFORE phase A so
// their HBM/L2 latency overlaps phase-A compute (compiler can't hoist across
// the barrier itself).
__global__ __launch_bounds__(192, 4)
void testam_wave(const float* __restrict__ input,
                 const float* __restrict__ h0,
                 const float* __restrict__ h1,
                 const float* __restrict__ h2,
                 const float* __restrict__ input_query,
                 const _Float16* __restrict__ ws,
                 float* __restrict__ out)
{
    __shared__ __align__(16) uint s_mem_pk[3 * 64 * 4];   // [tb][lane][4 dwords]
    __shared__ float s_nm[TT];

    const int tid  = threadIdx.x;
    const int e    = tid >> 6;          // wave id = expert
    const int lane = tid & 63;
    const int r = lane & 15, g = lane >> 4;
    const size_t bn = blockIdx.x;

    const int laneA = (g & 1) * 32 + r;   // used only by the shfl fallback
    const bool hiT = (g >= 2);

    // ===== prefetch: issue h + WV loads (raw; consumed after the barrier) ===
    const float* hp = (e == 0) ? h0 : (e == 1 ? h1 : h2);
    const float* hb = hp + bn * (size_t)(TT * HID);
    float4 hA_[3][2], hB_[3][2];
    #pragma unroll
    for (int tb = 0; tb < 3; ++tb)
        #pragma unroll
        for (int kk = 0; kk < 2; ++kk) {
            const float* src = hb + (tb * 16 + r) * HID + kk * 32 + g * 8;
            hA_[tb][kk] = *(const float4*)src;
            hB_[tb][kk] = *(const float4*)(src + 4);
        }
    half8 WV[2][2];
    #pragma unroll
    for (int kk = 0; kk < 2; ++kk)
        #pragma unroll
        for (int nb = 0; nb < 2; ++nb)
            WV[kk][nb] = *(const half8*)(ws + WS_WV + e * 2048 + (size_t)((kk * 2 + nb) * 64 + lane) * 8);

    // ===== phase A, 1/3 per wave (tb = e): memories + norms -> LDS ==========
    {
        const int tb = e;
        half8 memA0 = *(const half8*)(ws + WS_MEMA + (size_t)lane * 8);
        half8 memA1 = *(const half8*)(ws + WS_MEMA + (size_t)(64 + lane) * 8);
        half8 memB0 = *(const half8*)(ws + WS_MEMB + (size_t)lane * 8);
        half8 memB1 = *(const half8*)(ws + WS_MEMB + (size_t)(64 + lane) * 8);

        float4 iqa = *(const float4*)(input_query + g * 8);
        float4 iqb = *(const float4*)(input_query + g * 8 + 4);
        float4 iqc = *(const float4*)(input_query + 32 + g * 8);
        float4 iqd = *(const float4*)(input_query + 32 + g * 8 + 4);
        float iq0[8] = {iqa.x, iqa.y, iqa.z, iqa.w, iqb.x, iqb.y, iqb.z, iqb.w};
        float iq1[8] = {iqc.x, iqc.y, iqc.z, iqc.w, iqd.x, iqd.y, iqd.z, iqd.w};

        const float2 in2 = *(const float2*)(input + bn * 96 + (16 * tb + r) * 2);
        float f[8];
        #pragma unroll
        for (int j = 0; j < 8; ++j) f[j] = in2.x * iq0[j] + in2.y * iq1[j];
        half8 qb = mk8(pk2(f[0], f[1]), pk2(f[2], f[3]), pk2(f[4], f[5]), pk2(f[6], f[7]));
        floatx4 Em0 = __builtin_amdgcn_mfma_f32_16x16x32_f16(memA0, qb, (floatx4)0.f, 0, 0, 0);
        floatx4 Em1 = __builtin_amdgcn_mfma_f32_16x16x32_f16(memA1, qb, (floatx4)0.f, 0, 0, 0);

        float mx = Em0[0];
        #pragma unroll
        for (int rr = 1; rr < 4; ++rr) mx = fmaxf(mx, Em0[rr]);
        #pragma unroll
        for (int rr = 0; rr < 4; ++rr) mx = fmaxf(mx, Em1[rr]);
        mx = wavemax_1632(mx);
        uint pA0[2], pA1[2];
        #pragma unroll
        for (int d = 0; d < 2; ++d) {
            pA0[d] = pk2(__expf(Em0[2 * d] - mx), __expf(Em0[2 * d + 1] - mx));
            pA1[d] = pk2(__expf(Em1[2 * d] - mx), __expf(Em1[2 * d + 1] - mx));
        }
        half8 pA = regroup2(pA0, pA1, laneA, hiT);
        floatx4 m0 = __builtin_amdgcn_mfma_f32_16x16x32_f16(pA, memB0, (floatx4)0.f, 0, 0, 0);
        floatx4 m1 = __builtin_amdgcn_mfma_f32_16x16x32_f16(pA, memB1, (floatx4)0.f, 0, 0, 0);
        #pragma unroll
        for (int rr = 0; rr < 4; ++rr) {
            float nm = dpp_reduce_f32(m0[rr] * m0[rr] + m1[rr] * m1[rr]);
            if (r == 0) s_nm[16 * tb + 4 * g + rr] = nm;
        }
        uint4t mp = { pk2(m0[0], m0[1]), pk2(m0[2], m0[3]),
                      pk2(m1[0], m1[1]), pk2(m1[2], m1[3]) };
        *(uint4t*)&s_mem_pk[(tb * 64 + lane) * 4] = mp;
    }
    __syncthreads();

    // ===== expert body (h data already in flight/registers) =================
    half8 Ah[3][2];
    #pragma unroll
    for (int tb = 0; tb < 3; ++tb)
        #pragma unroll
        for (int kk = 0; kk < 2; ++kk) {
            float4 x0 = hA_[tb][kk], x1 = hB_[tb][kk];
            Ah[tb][kk] = mk8(pk2(x0.x, x0.y), pk2(x0.z, x0.w),
                             pk2(x1.x, x1.y), pk2(x1.z, x1.w));
        }

    floatx4 E[3][3];
    #pragma unroll
    for (int tb = 0; tb < 3; ++tb)
        #pragma unroll
        for (int nb = 0; nb < 3; ++nb) E[tb][nb] = (floatx4)0.f;

    #pragma unroll
    for (int kk = 0; kk < 2; ++kk) {
        floatx4 Gacc[2][3];
        #pragma unroll
        for (int t = 0; t < 2; ++t)
            #pragma unroll
            for (int nb = 0; nb < 3; ++nb) Gacc[t][nb] = (floatx4)0.f;
        #pragma unroll
        for (int tbL = 0; tbL < 2; ++tbL) {
            const int tbG = kk * 2 + tbL;
            #pragma unroll
            for (int ak = 0; ak < 2; ++ak) {
                half8 Mhi = *(const half8*)(ws + WS_M +
                    (size_t)((((e * 2 + 0) * 4 + tbG) * 2 + ak) * 64 + lane) * 8);
                #pragma unroll
                for (int nb = 0; nb < 3; ++nb)
                    Gacc[tbL][nb] = __builtin_amdgcn_mfma_f32_16x16x32_f16(Mhi, Ah[nb][ak], Gacc[tbL][nb], 0, 0, 0);
            }
        }
        #pragma unroll
        for (int nb = 0; nb < 3; ++nb) {
            uint p0[2], p1[2];
            #pragma unroll
            for (int d = 0; d < 2; ++d) {
                p0[d] = pk2(Gacc[0][nb][2 * d], Gacc[0][nb][2 * d + 1]);
                p1[d] = pk2(Gacc[1][nb][2 * d], Gacc[1][nb][2 * d + 1]);
            }
            half8 Bh = regroup2(p0, p1, laneA, hiT);
            #pragma unroll
            for (int tb = 0; tb < 3; ++tb)
                E[tb][nb] = __builtin_amdgcn_mfma_f32_16x16x32_f16(Ah[tb][kk], Bh, E[tb][nb], 0, 0, 0);
        }
    }

    #pragma unroll
    for (int nb = 0; nb < 3; ++nb) {
        float m = E[0][nb][0];
        #pragma unroll
        for (int tb = 0; tb < 3; ++tb)
            #pragma unroll
            for (int rr = 0; rr < 4; ++rr) m = fmaxf(m, E[tb][nb][rr]);
        m = wavemax_1632(m);
        #pragma unroll
        for (int tb = 0; tb < 3; ++tb)
            #pragma unroll
            for (int rr = 0; rr < 4; ++rr) E[tb][nb][rr] = __expf(E[tb][nb][rr] - m);
    }

    half8 PF[3][2];
    #pragma unroll
    for (int tbT = 0; tbT < 3; ++tbT) {
        uint pk[3][2];
        #pragma unroll
        for (int t = 0; t < 3; ++t)
            #pragma unroll
            for (int d = 0; d < 2; ++d)
                pk[t][d] = pk2(E[t][tbT][2 * d], E[t][tbT][2 * d + 1]);
        PF[tbT][0] = regroup2(pk[0], pk[1], laneA, hiT);
        PF[tbT][1] = regroup1pad(pk[2], laneA, hiT);
    }

    half8 vb[2][2];
    {
        floatx4 vacc[3][2];
        #pragma unroll
        for (int tb = 0; tb < 3; ++tb) { vacc[tb][0] = (floatx4)0.f; vacc[tb][1] = (floatx4)0.f; }
        #pragma unroll
        for (int kk = 0; kk < 2; ++kk)
            #pragma unroll
            for (int tb = 0; tb < 3; ++tb)
                #pragma unroll
                for (int nb = 0; nb < 2; ++nb)
                    vacc[tb][nb] = __builtin_amdgcn_mfma_f32_16x16x32_f16(Ah[tb][kk], WV[kk][nb], vacc[tb][nb], 0, 0, 0);
        #pragma unroll
        for (int nb = 0; nb < 2; ++nb) {
            uint pkv[3][2];
            #pragma unroll
            for (int tb = 0; tb < 3; ++tb)
                #pragma unroll
                for (int d = 0; d < 2; ++d)
                    pkv[tb][d] = pk2(vacc[tb][nb][2 * d], vacc[tb][nb][2 * d + 1]);
            vb[nb][0] = regroup2(pkv[0], pkv[1], laneA, hiT);
            vb[nb][1] = regroup1pad(pkv[2], laneA, hiT);
        }
    }

    floatx4 att[3][2];
    #pragma unroll
    for (int tb = 0; tb < 3; ++tb) { att[tb][0] = (floatx4)0.f; att[tb][1] = (floatx4)0.f; }
    #pragma unroll
    for (int kk = 0; kk < 2; ++kk)
        #pragma unroll
        for (int tb = 0; tb < 3; ++tb) {
            att[tb][0] = __builtin_amdgcn_mfma_f32_16x16x32_f16(PF[tb][kk], vb[0][kk], att[tb][0], 0, 0, 0);
            att[tb][1] = __builtin_amdgcn_mfma_f32_16x16x32_f16(PF[tb][kk], vb[1][kk], att[tb][1], 0, 0, 0);
        }

    // ===== cosine: mems/nm from LDS, (nu,nr) packed f16, DPP reduce =========
    #pragma unroll
    for (int tb = 0; tb < 3; ++tb) {
        uint4t mp = *(const uint4t*)&s_mem_pk[(tb * 64 + lane) * 4];
        #pragma unroll
        for (int rr = 0; rr < 4; ++rr) {
            int t = 16 * tb + 4 * g + rr;
            float a0 = att[tb][0][rr], a1 = att[tb][1][rr];
            float m0 = (rr & 1) ? f16hi(mp[rr >> 1]) : f16lo(mp[rr >> 1]);
            float m1 = (rr & 1) ? f16hi(mp[2 + (rr >> 1)]) : f16lo(mp[2 + (rr >> 1)]);
            float nu = a0 * m0 + a1 * m1;
            float nr = a0 * a0 + a1 * a1;
            uint nur = dpp_reduce_pk(pk2(nu * 0.015625f, nr * 0.015625f));
            if (r == 0) {
                float nuv = f16lo(nur), nrv = f16hi(nur);
                float den = fmaxf(8.f * sqrtf(nrv * s_nm[t]), 1e-8f);
                out[(bn * TT + t) * 3 + e] = 64.f * nuv / den;
            }
        }
    }
}

extern "C" void kernel_launch(void* const* d_in, const int* in_sizes, int n_in,
                              void* d_out, int out_size, void* d_ws, size_t ws_size,
                              hipStream_t stream) {
    const float* input       = (const float*)d_in[0];
    const float* h0          = (const float*)d_in[1];
    const float* h1          = (const float*)d_in[2];
    const float* h2          = (const float*)d_in[3];
    const float* memory      = (const float*)d_in[4];
    const float* input_query = (const float*)d_in[5];
    const float* hid_query   = (const float*)d_in[6];
    const float* key_w       = (const float*)d_in[7];
    const float* value_w     = (const float*)d_in[8];
    float* out = (float*)d_out;
    _Float16* ws = (_Float16*)d_ws;   // 65536 bytes used

    hipLaunchKernelGGL(prep_frags, dim3(3), dim3(256), 0, stream,
                       hid_query, key_w, value_w, memory, ws);
    hipLaunchKernelGGL(testam_wave, dim3(16 * 1024), dim3(192), 0, stream,
                       input, h0, h1, h2, input_query, ws, out);
}

// Round 16
// 178.185 us; speedup vs baseline: 1.3961x; 1.0040x over previous
//
#include <hip/hip_runtime.h>

typedef _Float16 half8 __attribute__((ext_vector_type(8)));
typedef __fp16 fp16x2 __attribute__((ext_vector_type(2)));
typedef float floatx4 __attribute__((ext_vector_type(4)));
typedef unsigned int uint;
typedef uint uint4t __attribute__((ext_vector_type(4)));

#if __has_builtin(__builtin_amdgcn_permlane16_swap) && __has_builtin(__builtin_amdgcn_permlane32_swap)
#define HAVE_PERMLANE 1
#else
#define HAVE_PERMLANE 0
#endif

namespace {
constexpr int TT = 48, HID = 64, MH = 32, MS = 20;
// d_ws offsets in half elements (total 32768 halves = 64 KiB)
constexpr int WS_WV   = 0;        // value_w B-frags: [e][kk][nb] * 512
constexpr int WS_MEMA = 6144;     // mem A-frags (rows s, zero s>=20): 1024
constexpr int WS_MEMB = 7168;     // mem B-frags (k=s, col m, zero s>=20): 1024
constexpr int WS_M    = 8192;     // M^T A-frags: [e][hl][tbG][ak] * 512 (hl=1 unused)
}

static __device__ inline uint pk2(float a, float b) {
    fp16x2 h = __builtin_amdgcn_cvt_pkrtz(a, b);
    return __builtin_bit_cast(uint, h);
}
static __device__ inline half8 mk8(uint a, uint b, uint c, uint d) {
    uint4t u = {a, b, c, d};
    return __builtin_bit_cast(half8, u);
}
static __device__ inline uint pkadd(uint a, uint b) {
    fp16x2 x = __builtin_bit_cast(fp16x2, a);
    fp16x2 y = __builtin_bit_cast(fp16x2, b);
    fp16x2 z = x + y;                      // v_pk_add_f16
    return __builtin_bit_cast(uint, z);
}
static __device__ inline float f16lo(uint u) {
    fp16x2 f = __builtin_bit_cast(fp16x2, u); return (float)f[0];
}
static __device__ inline float f16hi(uint u) {
    fp16x2 f = __builtin_bit_cast(fp16x2, u); return (float)f[1];
}
// DPP lane-permute (within 16-lane rows)
template<int CTRL>
static __device__ inline uint dpp_mov(uint x) {
    return (uint)__builtin_amdgcn_update_dpp(0, (int)x, CTRL, 0xF, 0xF, true);
}
static __device__ inline uint dpp_reduce_pk(uint v) {
    v = pkadd(v, dpp_mov<0x128>(v));   // +ror8
    v = pkadd(v, dpp_mov<0x124>(v));   // +ror4
    v = pkadd(v, dpp_mov<0x4E>(v));    // +xor2
    v = pkadd(v, dpp_mov<0xB1>(v));    // +xor1
    return v;
}
static __device__ inline float dpp_reduce_f32(float v) {
    #define STEP(C) { int t = __builtin_amdgcn_update_dpp(0, __builtin_bit_cast(int, v), C, 0xF, 0xF, true); \
                      v += __builtin_bit_cast(float, t); }
    STEP(0x128) STEP(0x124) STEP(0x4E) STEP(0xB1)
    #undef STEP
    return v;
}

#if HAVE_PERMLANE
// compiler-modeled dual-output swaps (builtin returns {new_vdst, new_src})
static __device__ inline void pl32swap(uint& a, uint& b) {
    auto r = __builtin_amdgcn_permlane32_swap(a, b, false, false);
    a = (uint)r[0]; b = (uint)r[1];
}
static __device__ inline void pl16swap(uint& a, uint& b) {
    auto r = __builtin_amdgcn_permlane16_swap(a, b, false, false);
    a = (uint)r[0]; b = (uint)r[1];
}
#endif

// C-layout -> fragment regroup. Target permutation (verified rounds 6-14):
// w[d][g,r] = p_{g>=2}[(g&1)*32+r], w[2+d][g,r] = p_{g>=2}[(g&1)*32+16+r]
static __device__ inline half8 regroup2(const uint p0[2], const uint p1[2],
                                        int laneA, bool hiT) {
#if HAVE_PERMLANE
    uint w0 = p0[0], w2 = p1[0];
    pl32swap(w0, w2); pl16swap(w0, w2);
    uint w1 = p0[1], w3 = p1[1];
    pl32swap(w1, w3); pl16swap(w1, w3);
    return mk8(w0, w1, w2, w3);
#else
    uint w[4];
    #pragma unroll
    for (int d = 0; d < 2; ++d) {
        int a0 = __shfl((int)p0[d], laneA);
        int a1 = __shfl((int)p1[d], laneA);
        int b0 = __shfl((int)p0[d], laneA + 16);
        int b1 = __shfl((int)p1[d], laneA + 16);
        w[d]     = hiT ? (uint)a1 : (uint)a0;
        w[2 + d] = hiT ? (uint)b1 : (uint)b0;
    }
    return mk8(w[0], w[1], w[2], w[3]);
#endif
}
static __device__ inline half8 regroup1pad(const uint p2[2], int laneA, bool hiT) {
#if HAVE_PERMLANE
    uint w0 = p2[0], w2 = 0u;
    pl32swap(w0, w2); pl16swap(w0, w2);
    uint w1 = p2[1], w3 = 0u;
    pl32swap(w1, w3); pl16swap(w1, w3);
    return mk8(w0, w1, w2, w3);
#else
    uint w[4];
    #pragma unroll
    for (int d = 0; d < 2; ++d) {
        int a2 = __shfl((int)p2[d], laneA);
        int b2 = __shfl((int)p2[d], laneA + 16);
        w[d]     = hiT ? 0u : (uint)a2;
        w[2 + d] = hiT ? 0u : (uint)b2;
    }
    return mk8(w[0], w[1], w[2], w[3]);
#endif
}
// max across lane-groups {r}, {16+r}, {32+r}, {48+r} -> all lanes
static __device__ inline float wavemax_1632(float m) {
#if HAVE_PERMLANE
    uint a = __builtin_bit_cast(uint, m), b = a;
    pl16swap(a, b);
    float x = fmaxf(__builtin_bit_cast(float, a), __builtin_bit_cast(float, b));
    a = __builtin_bit_cast(uint, x); b = a;
    pl32swap(a, b);
    return fmaxf(__builtin_bit_cast(float, a), __builtin_bit_cast(float, b));
#else
    m = fmaxf(m, __shfl_xor(m, 16));
    m = fmaxf(m, __shfl_xor(m, 32));
    return m;
#endif
}

// Prep: per-expert M = Wq*Wk^T (fp32) -> M^T A-frags; value_w B-frags; mem frags.
__global__ __launch_bounds__(256)
void prep_frags(const float* __restrict__ hid_query,
                const float* __restrict__ key_w,
                const float* __restrict__ value_w,
                const float* __restrict__ memory,
                _Float16* __restrict__ ws)
{
    const int e = blockIdx.x, tid = threadIdx.x;
    __shared__ float sWq[HID * MH], sWk[HID * MH], sM[HID * HID];
    for (int i = tid; i < HID * MH; i += 256) {
        sWq[i] = hid_query[e * HID * MH + i];
        sWk[i] = key_w[e * HID * MH + i];
    }
    __syncthreads();
    for (int i = tid; i < HID * HID; i += 256) {
        int a = i >> 6, b = i & 63;
        float acc = 0.f;
        #pragma unroll
        for (int m = 0; m < MH; ++m) acc = fmaf(sWq[a * MH + m], sWk[b * MH + m], acc);
        sM[i] = acc;
    }
    __syncthreads();
    for (int i = tid; i < 16 * 512; i += 256) {
        int j = i & 7, lane = (i >> 3) & 63, ak = (i >> 9) & 1, tbG = (i >> 10) & 3, hl = (i >> 12) & 1;
        float v = sM[(32 * ak + 8 * (lane >> 4) + j) * 64 + 16 * tbG + (lane & 15)];
        _Float16 hi = (_Float16)v;
        ws[WS_M + (size_t)((((e * 2 + hl) * 4 + tbG) * 2 + ak) << 9) + (i & 511)] =
            hl ? (_Float16)(v - (float)hi) : hi;
    }
    for (int i = tid; i < 2048; i += 256) {
        int j = i & 7, lane = (i >> 3) & 63, nb = (i >> 9) & 1, kk = (i >> 10) & 1;
        int h = kk * 32 + (lane >> 4) * 8 + j;
        int m = nb * 16 + (lane & 15);
        ws[WS_WV + e * 2048 + (i & 2047)] = (_Float16)value_w[((size_t)e * HID + h) * MH + m];
    }
    if (e == 0) {
        for (int i = tid; i < 1024; i += 256) {
            int j = i & 7, lane = (i >> 3) & 63, sb = i >> 9;
            int s = 16 * sb + (lane & 15);
            int m = (lane >> 4) * 8 + j;
            ws[WS_MEMA + i] = (s < MS) ? (_Float16)memory[s * MH + m] : (_Float16)0.f;
        }
        for (int i = tid; i < 1024; i += 256) {
            int j = i & 7, lane = (i >> 3) & 63, nb = i >> 9;
            int s = (lane >> 4) * 8 + j;
            int m = 16 * nb + (lane & 15);
            ws[WS_MEMB + i] = (s < MS) ? (_Float16)memory[s * MH + m] : (_Float16)0.f;
        }
    }
}

// Block = one bn, 3 waves = 3 experts. Load-issue order matters (vmcnt is an
// in-order counter): phase-A's own loads are issued FIRST, then the h/WV
// prefetch, so phase-A compute waits only for its inputs while the h loads
// stay in flight across phase A + the barrier.
__global__ __launch_bounds__(192, 4)
void testam_wave(const float* __restrict__ input,
                 const float* __restrict__ h0,
                 const float* __restrict__ h1,
                 const float* __restrict__ h2,
                 const float* __restrict__ input_query,
                 const _Float16* __restrict__ ws,
                 float* __restrict__ out)
{
    __shared__ __align__(16) uint s_mem_pk[3 * 64 * 4];   // [tb][lane][4 dwords]
    __shared__ float s_nm[TT];

    const int tid  = threadIdx.x;
    const int e    = tid >> 6;          // wave id = expert
    const int lane = tid & 63;
    const int r = lane & 15, g = lane >> 4;
    const size_t bn = blockIdx.x;

    const int laneA = (g & 1) * 32 + r;   // used only by the shfl fallback
    const bool hiT = (g >= 2);

    // ===== 1) phase-A load issues (consumed first) ==========================
    const int tbA = e;
    half8 memA0 = *(const half8*)(ws + WS_MEMA + (size_t)lane * 8);
    half8 memA1 = *(const half8*)(ws + WS_MEMA + (size_t)(64 + lane) * 8);
    half8 memB0 = *(const half8*)(ws + WS_MEMB + (size_t)lane * 8);
    half8 memB1 = *(const half8*)(ws + WS_MEMB + (size_t)(64 + lane) * 8);
    float4 iqa = *(const float4*)(input_query + g * 8);
    float4 iqb = *(const float4*)(input_query + g * 8 + 4);
    float4 iqc = *(const float4*)(input_query + 32 + g * 8);
    float4 iqd = *(const float4*)(input_query + 32 + g * 8 + 4);
    const float2 in2 = *(const float2*)(input + bn * 96 + (16 * tbA + r) * 2);

    // ===== 2) h + WV prefetch (consumed after the barrier) ==================
    const float* hp = (e == 0) ? h0 : (e == 1 ? h1 : h2);
    const float* hb = hp + bn * (size_t)(TT * HID);
    float4 hA_[3][2], hB_[3][2];
    #pragma unroll
    for (int tb = 0; tb < 3; ++tb)
        #pragma unroll
        for (int kk = 0; kk < 2; ++kk) {
            const float* src = hb + (tb * 16 + r) * HID + kk * 32 + g * 8;
            hA_[tb][kk] = *(const float4*)src;
            hB_[tb][kk] = *(const float4*)(src + 4);
        }
    half8 WV[2][2];
    #pragma unroll
    for (int kk = 0; kk < 2; ++kk)
        #pragma unroll
        for (int nb = 0; nb < 2; ++nb)
            WV[kk][nb] = *(const half8*)(ws + WS_WV + e * 2048 + (size_t)((kk * 2 + nb) * 64 + lane) * 8);

    // ===== 3) phase A compute, 1/3 per wave (tb = e) -> LDS =================
    {
        float iq0[8] = {iqa.x, iqa.y, iqa.z, iqa.w, iqb.x, iqb.y, iqb.z, iqb.w};
        float iq1[8] = {iqc.x, iqc.y, iqc.z, iqc.w, iqd.x, iqd.y, iqd.z, iqd.w};
        float f[8];
        #pragma unroll
        for (int j = 0; j < 8; ++j) f[j] = in2.x * iq0[j] + in2.y * iq1[j];
        half8 qb = mk8(pk2(f[0], f[1]), pk2(f[2], f[3]), pk2(f[4], f[5]), pk2(f[6], f[7]));
        floatx4 Em0 = __builtin_amdgcn_mfma_f32_16x16x32_f16(memA0, qb, (floatx4)0.f, 0, 0, 0);
        floatx4 Em1 = __builtin_amdgcn_mfma_f32_16x16x32_f16(memA1, qb, (floatx4)0.f, 0, 0, 0);

        float mx = Em0[0];
        #pragma unroll
        for (int rr = 1; rr < 4; ++rr) mx = fmaxf(mx, Em0[rr]);
        #pragma unroll
        for (int rr = 0; rr < 4; ++rr) mx = fmaxf(mx, Em1[rr]);
        mx = wavemax_1632(mx);
        uint pA0[2], pA1[2];
        #pragma unroll
        for (int d = 0; d < 2; ++d) {
            pA0[d] = pk2(__expf(Em0[2 * d] - mx), __expf(Em0[2 * d + 1] - mx));
            pA1[d] = pk2(__expf(Em1[2 * d] - mx), __expf(Em1[2 * d + 1] - mx));
        }
        half8 pA = regroup2(pA0, pA1, laneA, hiT);
        floatx4 m0 = __builtin_amdgcn_mfma_f32_16x16x32_f16(pA, memB0, (floatx4)0.f, 0, 0, 0);
        floatx4 m1 = __builtin_amdgcn_mfma_f32_16x16x32_f16(pA, memB1, (floatx4)0.f, 0, 0, 0);
        #pragma unroll
        for (int rr = 0; rr < 4; ++rr) {
            float nm = dpp_reduce_f32(m0[rr] * m0[rr] + m1[rr] * m1[rr]);
            if (r == 0) s_nm[16 * tbA + 4 * g + rr] = nm;
        }
        uint4t mp = { pk2(m0[0], m0[1]), pk2(m0[2], m0[3]),
                      pk2(m1[0], m1[1]), pk2(m1[2], m1[3]) };
        *(uint4t*)&s_mem_pk[(tbA * 64 + lane) * 4] = mp;
    }
    __syncthreads();

    // ===== expert body (h data already in registers) ========================
    half8 Ah[3][2];
    #pragma unroll
    for (int tb = 0; tb < 3; ++tb)
        #pragma unroll
        for (int kk = 0; kk < 2; ++kk) {
            float4 x0 = hA_[tb][kk], x1 = hB_[tb][kk];
            Ah[tb][kk] = mk8(pk2(x0.x, x0.y), pk2(x0.z, x0.w),
                             pk2(x1.x, x1.y), pk2(x1.z, x1.w));
        }

    floatx4 E[3][3];
    #pragma unroll
    for (int tb = 0; tb < 3; ++tb)
        #pragma unroll
        for (int nb = 0; nb < 3; ++nb) E[tb][nb] = (floatx4)0.f;

    #pragma unroll
    for (int kk = 0; kk < 2; ++kk) {
        floatx4 Gacc[2][3];
        #pragma unroll
        for (int t = 0; t < 2; ++t)
            #pragma unroll
            for (int nb = 0; nb < 3; ++nb) Gacc[t][nb] = (floatx4)0.f;
        #pragma unroll
        for (int tbL = 0; tbL < 2; ++tbL) {
            const int tbG = kk * 2 + tbL;
            #pragma unroll
            for (int ak = 0; ak < 2; ++ak) {
                half8 Mhi = *(const half8*)(ws + WS_M +
                    (size_t)((((e * 2 + 0) * 4 + tbG) * 2 + ak) * 64 + lane) * 8);
                #pragma unroll
                for (int nb = 0; nb < 3; ++nb)
                    Gacc[tbL][nb] = __builtin_amdgcn_mfma_f32_16x16x32_f16(Mhi, Ah[nb][ak], Gacc[tbL][nb], 0, 0, 0);
            }
        }
        #pragma unroll
        for (int nb = 0; nb < 3; ++nb) {
            uint p0[2], p1[2];
            #pragma unroll
            for (int d = 0; d < 2; ++d) {
                p0[d] = pk2(Gacc[0][nb][2 * d], Gacc[0][nb][2 * d + 1]);
                p1[d] = pk2(Gacc[1][nb][2 * d], Gacc[1][nb][2 * d + 1]);
            }
            half8 Bh = regroup2(p0, p1, laneA, hiT);
            #pragma unroll
            for (int tb = 0; tb < 3; ++tb)
                E[tb][nb] = __builtin_amdgcn_mfma_f32_16x16x32_f16(Ah[tb][kk], Bh, E[tb][nb], 0, 0, 0);
        }
    }

    #pragma unroll
    for (int nb = 0; nb < 3; ++nb) {
        float m = E[0][nb][0];
        #pragma unroll
        for (int tb = 0; tb < 3; ++tb)
            #pragma unroll
            for (int rr = 0; rr < 4; ++rr) m = fmaxf(m, E[tb][nb][rr]);
        m = wavemax_1632(m);
        #pragma unroll
        for (int tb = 0; tb < 3; ++tb)
            #pragma unroll
            for (int rr = 0; rr < 4; ++rr) E[tb][nb][rr] = __expf(E[tb][nb][rr] - m);
    }

    half8 PF[3][2];
    #pragma unroll
    for (int tbT = 0; tbT < 3; ++tbT) {
        uint pk[3][2];
        #pragma unroll
        for (int t = 0; t < 3; ++t)
            #pragma unroll
            for (int d = 0; d < 2; ++d)
                pk[t][d] = pk2(E[t][tbT][2 * d], E[t][tbT][2 * d + 1]);
        PF[tbT][0] = regroup2(pk[0], pk[1], laneA, hiT);
        PF[tbT][1] = regroup1pad(pk[2], laneA, hiT);
    }

    half8 vb[2][2];
    {
        floatx4 vacc[3][2];
        #pragma unroll
        for (int tb = 0; tb < 3; ++tb) { vacc[tb][0] = (floatx4)0.f; vacc[tb][1] = (floatx4)0.f; }
        #pragma unroll
        for (int kk = 0; kk < 2; ++kk)
            #pragma unroll
            for (int tb = 0; tb < 3; ++tb)
                #pragma unroll
                for (int nb = 0; nb < 2; ++nb)
                    vacc[tb][nb] = __builtin_amdgcn_mfma_f32_16x16x32_f16(Ah[tb][kk], WV[kk][nb], vacc[tb][nb], 0, 0, 0);
        #pragma unroll
        for (int nb = 0; nb < 2; ++nb) {
            uint pkv[3][2];
            #pragma unroll
            for (int tb = 0; tb < 3; ++tb)
                #pragma unroll
                for (int d = 0; d < 2; ++d)
                    pkv[tb][d] = pk2(vacc[tb][nb][2 * d], vacc[tb][nb][2 * d + 1]);
            vb[nb][0] = regroup2(pkv[0], pkv[1], laneA, hiT);
            vb[nb][1] = regroup1pad(pkv[2], laneA, hiT);
        }
    }

    floatx4 att[3][2];
    #pragma unroll
    for (int tb = 0; tb < 3; ++tb) { att[tb][0] = (floatx4)0.f; att[tb][1] = (floatx4)0.f; }
    #pragma unroll
    for (int kk = 0; kk < 2; ++kk)
        #pragma unroll
        for (int tb = 0; tb < 3; ++tb) {
            att[tb][0] = __builtin_amdgcn_mfma_f32_16x16x32_f16(PF[tb][kk], vb[0][kk], att[tb][0], 0, 0, 0);
            att[tb][1] = __builtin_amdgcn_mfma_f32_16x16x32_f16(PF[tb][kk], vb[1][kk], att[tb][1], 0, 0, 0);
        }

    // ===== cosine: mems/nm from LDS, (nu,nr) packed f16, DPP reduce =========
    #pragma unroll
    for (int tb = 0; tb < 3; ++tb) {
        uint4t mp = *(const uint4t*)&s_mem_pk[(tb * 64 + lane) * 4];
        #pragma unroll
        for (int rr = 0; rr < 4; ++rr) {
            int t = 16 * tb + 4 * g + rr;
            float a0 = att[tb][0][rr], a1 = att[tb][1][rr];
            float m0 = (rr & 1) ? f16hi(mp[rr >> 1]) : f16lo(mp[rr >> 1]);
            float m1 = (rr & 1) ? f16hi(mp[2 + (rr >> 1)]) : f16lo(mp[2 + (rr >> 1)]);
            float nu = a0 * m0 + a1 * m1;
            float nr = a0 * a0 + a1 * a1;
            uint nur = dpp_reduce_pk(pk2(nu * 0.015625f, nr * 0.015625f));
            if (r == 0) {
                float nuv = f16lo(nur), nrv = f16hi(nur);
                float den = fmaxf(8.f * sqrtf(nrv * s_nm[t]), 1e-8f);
                out[(bn * TT + t) * 3 + e] = 64.f * nuv / den;
            }
        }
    }
}

extern "C" void kernel_launch(void* const* d_in, const int* in_sizes, int n_in,
                              void* d_out, int out_size, void* d_ws, size_t ws_size,
                              hipStream_t stream) {
    const float* input       = (const float*)d_in[0];
    const float* h0          = (const float*)d_in[1];
    const float* h1          = (const float*)d_in[2];
    const float* h2          = (const float*)d_in[3];
    const float* memory      = (const float*)d_in[4];
    const float* input_query = (const float*)d_in[5];
    const float* hid_query   = (const float*)d_in[6];
    const float* key_w       = (const float*)d_in[7];
    const float* value_w     = (const float*)d_in[8];
    float* out = (float*)d_out;
    _Float16* ws = (_Float16*)d_ws;   // 65536 bytes used

    hipLaunchKernelGGL(prep_frags, dim3(3), dim3(256), 0, stream,
                       hid_query, key_w, value_w, memory, ws);
    hipLaunchKernelGGL(testam_wave, dim3(16 * 1024), dim3(192), 0, stream,
                       input, h0, h1, h2, input_query, ws, out);
}

// Round 17
// 164.499 us; speedup vs baseline: 1.5123x; 1.0832x over previous
//
#include <hip/hip_runtime.h>

typedef _Float16 half8 __attribute__((ext_vector_type(8)));
typedef __fp16 fp16x2 __attribute__((ext_vector_type(2)));
typedef float floatx4 __attribute__((ext_vector_type(4)));
typedef unsigned int uint;
typedef uint uint4t __attribute__((ext_vector_type(4)));

#if __has_builtin(__builtin_amdgcn_permlane16_swap) && __has_builtin(__builtin_amdgcn_permlane32_swap)
#define HAVE_PERMLANE 1
#else
#define HAVE_PERMLANE 0
#endif

namespace {
constexpr int TT = 48, HID = 64, MH = 32, MS = 20;
// d_ws offsets in half elements (total 32768 halves = 64 KiB)
constexpr int WS_WV   = 0;        // value_w B-frags: [e][kk][nb] * 512
constexpr int WS_MEMA = 6144;     // mem A-frags (rows s, zero s>=20): 1024
constexpr int WS_MEMB = 7168;     // mem B-frags (k=s, col m, zero s>=20): 1024
constexpr int WS_M    = 8192;     // M^T A-frags: [e][hl][tbG][ak] * 512 (hl=1 unused)
}

static __device__ inline uint pk2(float a, float b) {
    fp16x2 h = __builtin_amdgcn_cvt_pkrtz(a, b);
    return __builtin_bit_cast(uint, h);
}
static __device__ inline half8 mk8(uint a, uint b, uint c, uint d) {
    uint4t u = {a, b, c, d};
    return __builtin_bit_cast(half8, u);
}
static __device__ inline uint pkadd(uint a, uint b) {
    fp16x2 x = __builtin_bit_cast(fp16x2, a);
    fp16x2 y = __builtin_bit_cast(fp16x2, b);
    fp16x2 z = x + y;                      // v_pk_add_f16
    return __builtin_bit_cast(uint, z);
}
static __device__ inline float f16lo(uint u) {
    fp16x2 f = __builtin_bit_cast(fp16x2, u); return (float)f[0];
}
static __device__ inline float f16hi(uint u) {
    fp16x2 f = __builtin_bit_cast(fp16x2, u); return (float)f[1];
}
// DPP lane-permute (within 16-lane rows)
template<int CTRL>
static __device__ inline uint dpp_mov(uint x) {
    return (uint)__builtin_amdgcn_update_dpp(0, (int)x, CTRL, 0xF, 0xF, true);
}
static __device__ inline uint dpp_reduce_pk(uint v) {
    v = pkadd(v, dpp_mov<0x128>(v));   // +ror8
    v = pkadd(v, dpp_mov<0x124>(v));   // +ror4
    v = pkadd(v, dpp_mov<0x4E>(v));    // +xor2
    v = pkadd(v, dpp_mov<0xB1>(v));    // +xor1
    return v;
}
static __device__ inline float dpp_reduce_f32(float v) {
    #define STEP(C) { int t = __builtin_amdgcn_update_dpp(0, __builtin_bit_cast(int, v), C, 0xF, 0xF, true); \
                      v += __builtin_bit_cast(float, t); }
    STEP(0x128) STEP(0x124) STEP(0x4E) STEP(0xB1)
    #undef STEP
    return v;
}

#if HAVE_PERMLANE
// compiler-modeled dual-output swaps (builtin returns {new_vdst, new_src})
static __device__ inline void pl32swap(uint& a, uint& b) {
    auto r = __builtin_amdgcn_permlane32_swap(a, b, false, false);
    a = (uint)r[0]; b = (uint)r[1];
}
static __device__ inline void pl16swap(uint& a, uint& b) {
    auto r = __builtin_amdgcn_permlane16_swap(a, b, false, false);
    a = (uint)r[0]; b = (uint)r[1];
}
#endif

// C-layout -> fragment regroup. Target permutation (verified rounds 6-14):
// w[d][g,r] = p_{g>=2}[(g&1)*32+r], w[2+d][g,r] = p_{g>=2}[(g&1)*32+16+r]
static __device__ inline half8 regroup2(const uint p0[2], const uint p1[2],
                                        int laneA, bool hiT) {
#if HAVE_PERMLANE
    uint w0 = p0[0], w2 = p1[0];
    pl32swap(w0, w2); pl16swap(w0, w2);
    uint w1 = p0[1], w3 = p1[1];
    pl32swap(w1, w3); pl16swap(w1, w3);
    return mk8(w0, w1, w2, w3);
#else
    uint w[4];
    #pragma unroll
    for (int d = 0; d < 2; ++d) {
        int a0 = __shfl((int)p0[d], laneA);
        int a1 = __shfl((int)p1[d], laneA);
        int b0 = __shfl((int)p0[d], laneA + 16);
        int b1 = __shfl((int)p1[d], laneA + 16);
        w[d]     = hiT ? (uint)a1 : (uint)a0;
        w[2 + d] = hiT ? (uint)b1 : (uint)b0;
    }
    return mk8(w[0], w[1], w[2], w[3]);
#endif
}
static __device__ inline half8 regroup1pad(const uint p2[2], int laneA, bool hiT) {
#if HAVE_PERMLANE
    uint w0 = p2[0], w2 = 0u;
    pl32swap(w0, w2); pl16swap(w0, w2);
    uint w1 = p2[1], w3 = 0u;
    pl32swap(w1, w3); pl16swap(w1, w3);
    return mk8(w0, w1, w2, w3);
#else
    uint w[4];
    #pragma unroll
    for (int d = 0; d < 2; ++d) {
        int a2 = __shfl((int)p2[d], laneA);
        int b2 = __shfl((int)p2[d], laneA + 16);
        w[d]     = hiT ? 0u : (uint)a2;
        w[2 + d] = hiT ? 0u : (uint)b2;
    }
    return mk8(w[0], w[1], w[2], w[3]);
#endif
}
// max across lane-groups {r}, {16+r}, {32+r}, {48+r} -> all lanes
static __device__ inline float wavemax_1632(float m) {
#if HAVE_PERMLANE
    uint a = __builtin_bit_cast(uint, m), b = a;
    pl16swap(a, b);
    float x = fmaxf(__builtin_bit_cast(float, a), __builtin_bit_cast(float, b));
    a = __builtin_bit_cast(uint, x); b = a;
    pl32swap(a, b);
    return fmaxf(__builtin_bit_cast(float, a), __builtin_bit_cast(float, b));
#else
    m = fmaxf(m, __shfl_xor(m, 16));
    m = fmaxf(m, __shfl_xor(m, 32));
    return m;
#endif
}

// Prep: per-expert M = Wq*Wk^T (fp32) -> M^T A-frags; value_w B-frags; mem frags.
__global__ __launch_bounds__(256)
void prep_frags(const float* __restrict__ hid_query,
                const float* __restrict__ key_w,
                const float* __restrict__ value_w,
                const float* __restrict__ memory,
                _Float16* __restrict__ ws)
{
    const int e = blockIdx.x, tid = threadIdx.x;
    __shared__ float sWq[HID * MH], sWk[HID * MH], sM[HID * HID];
    for (int i = tid; i < HID * MH; i += 256) {
        sWq[i] = hid_query[e * HID * MH + i];
        sWk[i] = key_w[e * HID * MH + i];
    }
    __syncthreads();
    for (int i = tid; i < HID * HID; i += 256) {
        int a = i >> 6, b = i & 63;
        float acc = 0.f;
        #pragma unroll
        for (int m = 0; m < MH; ++m) acc = fmaf(sWq[a * MH + m], sWk[b * MH + m], acc);
        sM[i] = acc;
    }
    __syncthreads();
    for (int i = tid; i < 16 * 512; i += 256) {
        int j = i & 7, lane = (i >> 3) & 63, ak = (i >> 9) & 1, tbG = (i >> 10) & 3, hl = (i >> 12) & 1;
        float v = sM[(32 * ak + 8 * (lane >> 4) + j) * 64 + 16 * tbG + (lane & 15)];
        _Float16 hi = (_Float16)v;
        ws[WS_M + (size_t)((((e * 2 + hl) * 4 + tbG) * 2 + ak) << 9) + (i & 511)] =
            hl ? (_Float16)(v - (float)hi) : hi;
    }
    for (int i = tid; i < 2048; i += 256) {
        int j = i & 7, lane = (i >> 3) & 63, nb = (i >> 9) & 1, kk = (i >> 10) & 1;
        int h = kk * 32 + (lane >> 4) * 8 + j;
        int m = nb * 16 + (lane & 15);
        ws[WS_WV + e * 2048 + (i & 2047)] = (_Float16)value_w[((size_t)e * HID + h) * MH + m];
    }
    if (e == 0) {
        for (int i = tid; i < 1024; i += 256) {
            int j = i & 7, lane = (i >> 3) & 63, sb = i >> 9;
            int s = 16 * sb + (lane & 15);
            int m = (lane >> 4) * 8 + j;
            ws[WS_MEMA + i] = (s < MS) ? (_Float16)memory[s * MH + m] : (_Float16)0.f;
        }
        for (int i = tid; i < 1024; i += 256) {
            int j = i & 7, lane = (i >> 3) & 63, nb = i >> 9;
            int s = (lane >> 4) * 8 + j;
            int m = 16 * nb + (lane & 15);
            ws[WS_MEMB + i] = (s < MS) ? (_Float16)memory[s * MH + m] : (_Float16)0.f;
        }
    }
}

// Block = one bn, 3 waves = 3 experts. Phase-A loads first, h/WV prefetch in
// flight across phase A + barrier. Cosine finalization batched lane-parallel.
__global__ __launch_bounds__(192, 4)
void testam_wave(const float* __restrict__ input,
                 const float* __restrict__ h0,
                 const float* __restrict__ h1,
                 const float* __restrict__ h2,
                 const float* __restrict__ input_query,
                 const _Float16* __restrict__ ws,
                 float* __restrict__ out)
{
    __shared__ __align__(16) uint s_mem_pk[3 * 64 * 4];   // [tb][lane][4 dwords]
    __shared__ float s_nm[TT];

    const int tid  = threadIdx.x;
    const int e    = tid >> 6;          // wave id = expert
    const int lane = tid & 63;
    const int r = lane & 15, g = lane >> 4;
    const size_t bn = blockIdx.x;

    const int laneA = (g & 1) * 32 + r;   // used only by the shfl fallback
    const bool hiT = (g >= 2);

    // ===== 1) phase-A load issues (consumed first) ==========================
    const int tbA = e;
    half8 memA0 = *(const half8*)(ws + WS_MEMA + (size_t)lane * 8);
    half8 memA1 = *(const half8*)(ws + WS_MEMA + (size_t)(64 + lane) * 8);
    half8 memB0 = *(const half8*)(ws + WS_MEMB + (size_t)lane * 8);
    half8 memB1 = *(const half8*)(ws + WS_MEMB + (size_t)(64 + lane) * 8);
    float4 iqa = *(const float4*)(input_query + g * 8);
    float4 iqb = *(const float4*)(input_query + g * 8 + 4);
    float4 iqc = *(const float4*)(input_query + 32 + g * 8);
    float4 iqd = *(const float4*)(input_query + 32 + g * 8 + 4);
    const float2 in2 = *(const float2*)(input + bn * 96 + (16 * tbA + r) * 2);

    // ===== 2) h + WV prefetch (consumed after the barrier) ==================
    const float* hp = (e == 0) ? h0 : (e == 1 ? h1 : h2);
    const float* hb = hp + bn * (size_t)(TT * HID);
    float4 hA_[3][2], hB_[3][2];
    #pragma unroll
    for (int tb = 0; tb < 3; ++tb)
        #pragma unroll
        for (int kk = 0; kk < 2; ++kk) {
            const float* src = hb + (tb * 16 + r) * HID + kk * 32 + g * 8;
            hA_[tb][kk] = *(const float4*)src;
            hB_[tb][kk] = *(const float4*)(src + 4);
        }
    half8 WV[2][2];
    #pragma unroll
    for (int kk = 0; kk < 2; ++kk)
        #pragma unroll
        for (int nb = 0; nb < 2; ++nb)
            WV[kk][nb] = *(const half8*)(ws + WS_WV + e * 2048 + (size_t)((kk * 2 + nb) * 64 + lane) * 8);

    // ===== 3) phase A compute, 1/3 per wave (tb = e) -> LDS =================
    {
        float iq0[8] = {iqa.x, iqa.y, iqa.z, iqa.w, iqb.x, iqb.y, iqb.z, iqb.w};
        float iq1[8] = {iqc.x, iqc.y, iqc.z, iqc.w, iqd.x, iqd.y, iqd.z, iqd.w};
        float f[8];
        #pragma unroll
        for (int j = 0; j < 8; ++j) f[j] = in2.x * iq0[j] + in2.y * iq1[j];
        half8 qb = mk8(pk2(f[0], f[1]), pk2(f[2], f[3]), pk2(f[4], f[5]), pk2(f[6], f[7]));
        floatx4 Em0 = __builtin_amdgcn_mfma_f32_16x16x32_f16(memA0, qb, (floatx4)0.f, 0, 0, 0);
        floatx4 Em1 = __builtin_amdgcn_mfma_f32_16x16x32_f16(memA1, qb, (floatx4)0.f, 0, 0, 0);

        float mx = Em0[0];
        #pragma unroll
        for (int rr = 1; rr < 4; ++rr) mx = fmaxf(mx, Em0[rr]);
        #pragma unroll
        for (int rr = 0; rr < 4; ++rr) mx = fmaxf(mx, Em1[rr]);
        mx = wavemax_1632(mx);
        uint pA0[2], pA1[2];
        #pragma unroll
        for (int d = 0; d < 2; ++d) {
            pA0[d] = pk2(__expf(Em0[2 * d] - mx), __expf(Em0[2 * d + 1] - mx));
            pA1[d] = pk2(__expf(Em1[2 * d] - mx), __expf(Em1[2 * d + 1] - mx));
        }
        half8 pA = regroup2(pA0, pA1, laneA, hiT);
        floatx4 m0 = __builtin_amdgcn_mfma_f32_16x16x32_f16(pA, memB0, (floatx4)0.f, 0, 0, 0);
        floatx4 m1 = __builtin_amdgcn_mfma_f32_16x16x32_f16(pA, memB1, (floatx4)0.f, 0, 0, 0);
        #pragma unroll
        for (int rr = 0; rr < 4; ++rr) {
            float nm = dpp_reduce_f32(m0[rr] * m0[rr] + m1[rr] * m1[rr]);
            if (r == 0) s_nm[16 * tbA + 4 * g + rr] = nm;
        }
        uint4t mp = { pk2(m0[0], m0[1]), pk2(m0[2], m0[3]),
                      pk2(m1[0], m1[1]), pk2(m1[2], m1[3]) };
        *(uint4t*)&s_mem_pk[(tbA * 64 + lane) * 4] = mp;
    }
    __syncthreads();

    // ===== expert body (h data already in registers) ========================
    half8 Ah[3][2];
    #pragma unroll
    for (int tb = 0; tb < 3; ++tb)
        #pragma unroll
        for (int kk = 0; kk < 2; ++kk) {
            float4 x0 = hA_[tb][kk], x1 = hB_[tb][kk];
            Ah[tb][kk] = mk8(pk2(x0.x, x0.y), pk2(x0.z, x0.w),
                             pk2(x1.x, x1.y), pk2(x1.z, x1.w));
        }

    floatx4 E[3][3];
    #pragma unroll
    for (int tb = 0; tb < 3; ++tb)
        #pragma unroll
        for (int nb = 0; nb < 3; ++nb) E[tb][nb] = (floatx4)0.f;

    #pragma unroll
    for (int kk = 0; kk < 2; ++kk) {
        floatx4 Gacc[2][3];
        #pragma unroll
        for (int t = 0; t < 2; ++t)
            #pragma unroll
            for (int nb = 0; nb < 3; ++nb) Gacc[t][nb] = (floatx4)0.f;
        #pragma unroll
        for (int tbL = 0; tbL < 2; ++tbL) {
            const int tbG = kk * 2 + tbL;
            #pragma unroll
            for (int ak = 0; ak < 2; ++ak) {
                half8 Mhi = *(const half8*)(ws + WS_M +
                    (size_t)((((e * 2 + 0) * 4 + tbG) * 2 + ak) * 64 + lane) * 8);
                #pragma unroll
                for (int nb = 0; nb < 3; ++nb)
                    Gacc[tbL][nb] = __builtin_amdgcn_mfma_f32_16x16x32_f16(Mhi, Ah[nb][ak], Gacc[tbL][nb], 0, 0, 0);
            }
        }
        #pragma unroll
        for (int nb = 0; nb < 3; ++nb) {
            uint p0[2], p1[2];
            #pragma unroll
            for (int d = 0; d < 2; ++d) {
                p0[d] = pk2(Gacc[0][nb][2 * d], Gacc[0][nb][2 * d + 1]);
                p1[d] = pk2(Gacc[1][nb][2 * d], Gacc[1][nb][2 * d + 1]);
            }
            half8 Bh = regroup2(p0, p1, laneA, hiT);
            #pragma unroll
            for (int tb = 0; tb < 3; ++tb)
                E[tb][nb] = __builtin_amdgcn_mfma_f32_16x16x32_f16(Ah[tb][kk], Bh, E[tb][nb], 0, 0, 0);
        }
    }

    #pragma unroll
    for (int nb = 0; nb < 3; ++nb) {
        float m = E[0][nb][0];
        #pragma unroll
        for (int tb = 0; tb < 3; ++tb)
            #pragma unroll
            for (int rr = 0; rr < 4; ++rr) m = fmaxf(m, E[tb][nb][rr]);
        m = wavemax_1632(m);
        #pragma unroll
        for (int tb = 0; tb < 3; ++tb)
            #pragma unroll
            for (int rr = 0; rr < 4; ++rr) E[tb][nb][rr] = __expf(E[tb][nb][rr] - m);
    }

    half8 PF[3][2];
    #pragma unroll
    for (int tbT = 0; tbT < 3; ++tbT) {
        uint pk[3][2];
        #pragma unroll
        for (int t = 0; t < 3; ++t)
            #pragma unroll
            for (int d = 0; d < 2; ++d)
                pk[t][d] = pk2(E[t][tbT][2 * d], E[t][tbT][2 * d + 1]);
        PF[tbT][0] = regroup2(pk[0], pk[1], laneA, hiT);
        PF[tbT][1] = regroup1pad(pk[2], laneA, hiT);
    }

    half8 vb[2][2];
    {
        floatx4 vacc[3][2];
        #pragma unroll
        for (int tb = 0; tb < 3; ++tb) { vacc[tb][0] = (floatx4)0.f; vacc[tb][1] = (floatx4)0.f; }
        #pragma unroll
        for (int kk = 0; kk < 2; ++kk)
            #pragma unroll
            for (int tb = 0; tb < 3; ++tb)
                #pragma unroll
                for (int nb = 0; nb < 2; ++nb)
                    vacc[tb][nb] = __builtin_amdgcn_mfma_f32_16x16x32_f16(Ah[tb][kk], WV[kk][nb], vacc[tb][nb], 0, 0, 0);
        #pragma unroll
        for (int nb = 0; nb < 2; ++nb) {
            uint pkv[3][2];
            #pragma unroll
            for (int tb = 0; tb < 3; ++tb)
                #pragma unroll
                for (int d = 0; d < 2; ++d)
                    pkv[tb][d] = pk2(vacc[tb][nb][2 * d], vacc[tb][nb][2 * d + 1]);
            vb[nb][0] = regroup2(pkv[0], pkv[1], laneA, hiT);
            vb[nb][1] = regroup1pad(pkv[2], laneA, hiT);
        }
    }

    floatx4 att[3][2];
    #pragma unroll
    for (int tb = 0; tb < 3; ++tb) { att[tb][0] = (floatx4)0.f; att[tb][1] = (floatx4)0.f; }
    #pragma unroll
    for (int kk = 0; kk < 2; ++kk)
        #pragma unroll
        for (int tb = 0; tb < 3; ++tb) {
            att[tb][0] = __builtin_amdgcn_mfma_f32_16x16x32_f16(PF[tb][kk], vb[0][kk], att[tb][0], 0, 0, 0);
            att[tb][1] = __builtin_amdgcn_mfma_f32_16x16x32_f16(PF[tb][kk], vb[1][kk], att[tb][1], 0, 0, 0);
        }

    // ===== cosine: 4 packed reduces per tb, then ONE lane-parallel finalize =
    // (reduce result is uniform over the 16 r-lanes; select rr=r&3 per lane
    //  via 3 cndmask and finalize 16 t-values at once; stores 12 -> 3)
    #pragma unroll
    for (int tb = 0; tb < 3; ++tb) {
        uint4t mp = *(const uint4t*)&s_mem_pk[(tb * 64 + lane) * 4];
        uint nur[4];
        #pragma unroll
        for (int rr = 0; rr < 4; ++rr) {
            float a0 = att[tb][0][rr], a1 = att[tb][1][rr];
            float m0 = (rr & 1) ? f16hi(mp[rr >> 1]) : f16lo(mp[rr >> 1]);
            float m1 = (rr & 1) ? f16hi(mp[2 + (rr >> 1)]) : f16lo(mp[2 + (rr >> 1)]);
            float nu = a0 * m0 + a1 * m1;
            float nr = a0 * a0 + a1 * a1;
            nur[rr] = dpp_reduce_pk(pk2(nu * 0.015625f, nr * 0.015625f));
        }
        uint s01 = (r & 1) ? nur[1] : nur[0];
        uint s23 = (r & 1) ? nur[3] : nur[2];
        uint sf  = (r & 2) ? s23 : s01;
        int t = 16 * tb + 4 * g + (r & 3);
        float nuv = f16lo(sf), nrv = f16hi(sf);
        float den = fmaxf(8.f * sqrtf(nrv * s_nm[t]), 1e-8f);
        float res = 64.f * nuv / den;
        if (r < 4) out[(bn * TT + t) * 3 + e] = res;
    }
}

extern "C" void kernel_launch(void* const* d_in, const int* in_sizes, int n_in,
                              void* d_out, int out_size, void* d_ws, size_t ws_size,
                              hipStream_t stream) {
    const float* input       = (const float*)d_in[0];
    const float* h0          = (const float*)d_in[1];
    const float* h1          = (const float*)d_in[2];
    const float* h2          = (const float*)d_in[3];
    const float* memory      = (const float*)d_in[4];
    const float* input_query = (const float*)d_in[5];
    const float* hid_query   = (const float*)d_in[6];
    const float* key_w       = (const float*)d_in[7];
    const float* value_w     = (const float*)d_in[8];
    float* out = (float*)d_out;
    _Float16* ws = (_Float16*)d_ws;   // 65536 bytes used

    hipLaunchKernelGGL(prep_frags, dim3(3), dim3(256), 0, stream,
                       hid_query, key_w, value_w, memory, ws);
    hipLaunchKernelGGL(testam_wave, dim3(16 * 1024), dim3(192), 0, stream,
                       input, h0, h1, h2, input_query, ws, out);
}